// Round 1
// baseline (5595.765 us; speedup 1.0000x reference)
//
#include <hip/hip_runtime.h>
#include <cstdint>
#include <cstddef>

// ---------------- problem constants ----------------
#define NU_C   20000
#define NI_C   8000
#define NTOT_C 28000          // NU+NI
#define NE_C   200000
#define B_C    4096
#define NPAD_C 8064           // NI padded to 63*128 target blocks

typedef unsigned short u16;
typedef unsigned int   u32;
typedef __bf16 bf16x8 __attribute__((ext_vector_type(8)));
typedef float  f32x4  __attribute__((ext_vector_type(4)));

static __device__ __forceinline__ u16 f2bf(float f) {
  u32 u = __float_as_uint(f);
  u32 r = u + 0x7fffu + ((u >> 16) & 1u);   // RNE
  return (u16)(r >> 16);
}

// ---------------- bf16 convert + row 1/norm (fp32) ----------------
template<int D>
__global__ void conv_kernel(const float* __restrict__ F, u16* __restrict__ Fb,
                            float* __restrict__ rn) {
  const int row = blockIdx.x;
  const int tid = threadIdx.x;
  float ss = 0.f;
  u16* dst = Fb + (size_t)row * D;
  if (row < NI_C) {
    const float* src = F + (size_t)row * D;
    for (int c = tid * 4; c < D; c += 1024) {
      float4 f = *(const float4*)(src + c);
      ss += f.x*f.x + f.y*f.y + f.z*f.z + f.w*f.w;
      ushort4 b; b.x = f2bf(f.x); b.y = f2bf(f.y); b.z = f2bf(f.z); b.w = f2bf(f.w);
      *(ushort4*)(dst + c) = b;
    }
  } else {                                    // zero padding rows
    for (int c = tid * 4; c < D; c += 1024) {
      ushort4 b; b.x = b.y = b.z = b.w = 0;
      *(ushort4*)(dst + c) = b;
    }
  }
  #pragma unroll
  for (int off = 32; off; off >>= 1) ss += __shfl_xor(ss, off);
  __shared__ float red[4];
  if ((tid & 63) == 0) red[tid >> 6] = ss;
  __syncthreads();
  if (tid == 0) {
    float s = red[0] + red[1] + red[2] + red[3];
    rn[row] = (row < NI_C) ? rsqrtf(s) : 0.f;
  }
}

// ---------------- fused bf16-MFMA Gram + per-row running top-10 ----------------
// Block: 256 thr (4 waves). 128 target rows/block (wave w owns 32: two 16-row frags).
// Candidates swept 64/iter; grid.y strips of 8 iters -> per-strip top10 lists.
// MFMA: A = candidates (m), B = targets (n): D[m][n], lane: n=lane&15 (fixed target),
// m = quad*4+reg  => per-lane top-10 over its candidate subset, static-index sorted insert.
#define CITERS_TOTAL 125      // 8000/64
#define ITERS_STRIP  8
#define NSTRIP       16

template<int D>
__launch_bounds__(256)
__global__ void simtopk_kernel(const u16* __restrict__ F, const float* __restrict__ rn,
                               float* __restrict__ tv, int* __restrict__ ti) {
  __shared__ __align__(16) char smem[40960];
  u16*   sB  = (u16*)smem;                 // targets [128][72] (pad 8 -> 2-way-free banks)
  u16*   sA  = (u16*)(smem + 18432);       // cands   [64][72]
  float* sRN = (float*)(smem + 27648);     // cand 1/norm [64]
  float* mval = (float*)smem;              // merge phase: [128][40]
  int*   midx = (int*)(smem + 20480);

  const int tid  = threadIdx.x;
  const int lane = tid & 63;
  const int wv   = tid >> 6;
  const int n15  = lane & 15;
  const int quad = lane >> 4;
  const int TB   = blockIdx.x * 128;
  const int it0  = blockIdx.y * ITERS_STRIP;
  const int it1  = (it0 + ITERS_STRIP < CITERS_TOTAL) ? (it0 + ITERS_STRIP) : CITERS_TOTAL;

  float bv[2][10];
  int   bi[2][10];
  #pragma unroll
  for (int tf = 0; tf < 2; ++tf)
    #pragma unroll
    for (int j = 0; j < 10; ++j) { bv[tf][j] = -1e30f; bi[tf][j] = 0; }

  for (int it = it0; it < it1; ++it) {
    const int c0 = it * 64;
    f32x4 acc[2][4];
    #pragma unroll
    for (int a = 0; a < 2; ++a)
      #pragma unroll
      for (int b = 0; b < 4; ++b) { f32x4 z = {0.f,0.f,0.f,0.f}; acc[a][b] = z; }

    for (int k0 = 0; k0 < D; k0 += 64) {
      __syncthreads();                       // protect LDS reuse (incl. sRN reads)
      #pragma unroll
      for (int rep = 0; rep < 4; ++rep) {    // stage targets: 1024 x 16B
        int cid = tid + rep * 256;
        int row = cid >> 3, seg = cid & 7;
        uint4 g = *(const uint4*)(F + (size_t)(TB + row) * D + k0 + seg * 8);
        *(uint4*)(sB + row * 72 + seg * 8) = g;
      }
      #pragma unroll
      for (int rep = 0; rep < 2; ++rep) {    // stage candidates: 512 x 16B
        int cid = tid + rep * 256;
        int row = cid >> 3, seg = cid & 7;
        uint4 g = *(const uint4*)(F + (size_t)(c0 + row) * D + k0 + seg * 8);
        *(uint4*)(sA + row * 72 + seg * 8) = g;
      }
      if (k0 == 0 && tid < 64) sRN[tid] = rn[c0 + tid];
      __syncthreads();
      #pragma unroll
      for (int ks = 0; ks < 2; ++ks) {
        bf16x8 bfrag[2], afrag[4];
        #pragma unroll
        for (int tf = 0; tf < 2; ++tf)
          bfrag[tf] = *(const bf16x8*)(sB + (wv*32 + tf*16 + n15) * 72 + ks*32 + quad*8);
        #pragma unroll
        for (int af = 0; af < 4; ++af)
          afrag[af] = *(const bf16x8*)(sA + (af*16 + n15) * 72 + ks*32 + quad*8);
        #pragma unroll
        for (int tf = 0; tf < 2; ++tf)
          #pragma unroll
          for (int af = 0; af < 4; ++af)
            acc[tf][af] = __builtin_amdgcn_mfma_f32_16x16x32_bf16(afrag[af], bfrag[tf], acc[tf][af], 0, 0, 0);
      }
    }
    // top-k update: value = dot * (1/|cand|)  (1/|target| constant per row: rank-invariant)
    #pragma unroll
    for (int af = 0; af < 4; ++af) {
      const float4 rn4 = *(const float4*)(sRN + af * 16 + quad * 4);
      const float rna[4] = {rn4.x, rn4.y, rn4.z, rn4.w};
      #pragma unroll
      for (int tf = 0; tf < 2; ++tf)
        #pragma unroll
        for (int r = 0; r < 4; ++r) {
          float v = acc[tf][af][r] * rna[r];
          int  ci = c0 + af * 16 + quad * 4 + r;
          if (v > bv[tf][9]) {               // sorted desc; static-index insertion
            bv[tf][9] = v; bi[tf][9] = ci;
            #pragma unroll
            for (int j = 9; j > 0; --j)
              if (bv[tf][j] > bv[tf][j-1]) {
                float tvv = bv[tf][j]; bv[tf][j] = bv[tf][j-1]; bv[tf][j-1] = tvv;
                int   tii = bi[tf][j]; bi[tf][j] = bi[tf][j-1]; bi[tf][j-1] = tii;
              }
          }
        }
    }
  }
  __syncthreads();                            // all compute done -> reuse LDS for merge
  #pragma unroll
  for (int tf = 0; tf < 2; ++tf) {
    int rl = wv * 32 + tf * 16 + n15;
    #pragma unroll
    for (int j = 0; j < 10; ++j) {
      mval[rl * 40 + quad * 10 + j] = bv[tf][j];
      midx[rl * 40 + quad * 10 + j] = bi[tf][j];
    }
  }
  __syncthreads();
  if (tid < 128) {                            // per-row: merge 4 quads' lists -> strip top-10
    const int rl = tid;
    float* mv = mval + rl * 40;
    int*   mi = midx + rl * 40;
    const size_t ob = (size_t)(TB + rl) * (NSTRIP * 10) + blockIdx.y * 10;
    #pragma unroll 1
    for (int s = 0; s < 10; ++s) {
      float m = mv[0]; int a = 0;
      for (int t = 1; t < 40; ++t) { float v = mv[t]; if (v > m) { m = v; a = t; } }
      tv[ob + s] = m; ti[ob + s] = mi[a];
      mv[a] = -1e30f;
    }
  }
}

// ---------------- merge 16 strips x 10 -> final top-10 indices ----------------
__global__ void merge_topk_kernel(const float* __restrict__ tv, const int* __restrict__ ti,
                                  int* __restrict__ idx) {
  __shared__ float fv[160];
  __shared__ int   fi[160];
  const int row = blockIdx.x;
  for (int t = threadIdx.x; t < 160; t += 64) {
    fv[t] = tv[(size_t)row * 160 + t];
    fi[t] = ti[(size_t)row * 160 + t];
  }
  __syncthreads();
  if (threadIdx.x == 0) {
    for (int s = 0; s < 10; ++s) {
      float m = fv[0]; int a = 0;
      for (int t = 1; t < 160; ++t) if (fv[t] > m) { m = fv[t]; a = t; }
      idx[row * 10 + s] = fi[a];
      fv[a] = -1e30f;
    }
  }
}

// ---------------- GCN pieces ----------------
__global__ void deg_count_kernel(const int* __restrict__ eu, const int* __restrict__ ei,
                                 float* deg) {
  int e = blockIdx.x * 256 + threadIdx.x;
  if (e < NE_C) {
    atomicAdd(&deg[eu[e]], 1.f);
    atomicAdd(&deg[NU_C + ei[e]], 1.f);
  }
}
__global__ void dinv_kernel(float* deg) {
  int n = blockIdx.x * 256 + threadIdx.x;
  if (n < NTOT_C) deg[n] = rsqrtf(fmaxf(deg[n], 1.f));
}

template<int D>
__global__ void gemm_xw_kernel(const float* __restrict__ F, const float* __restrict__ W,
                               float* __restrict__ x) {
  const int col = threadIdx.x & 63;
  const int ty  = threadIdx.x >> 6;
  const int r0  = blockIdx.x * 16 + ty * 4;
  const float* f0 = F + (size_t)r0 * D;
  float a0 = 0.f, a1 = 0.f, a2 = 0.f, a3 = 0.f;
  for (int k = 0; k < D; k += 4) {
    const float w0 = W[(k+0)*64 + col];
    const float w1 = W[(k+1)*64 + col];
    const float w2 = W[(k+2)*64 + col];
    const float w3 = W[(k+3)*64 + col];
    float4 fa = *(const float4*)(f0 + 0*(size_t)D + k);
    float4 fb = *(const float4*)(f0 + 1*(size_t)D + k);
    float4 fc = *(const float4*)(f0 + 2*(size_t)D + k);
    float4 fd = *(const float4*)(f0 + 3*(size_t)D + k);
    a0 += fa.x*w0 + fa.y*w1 + fa.z*w2 + fa.w*w3;
    a1 += fb.x*w0 + fb.y*w1 + fb.z*w2 + fb.w*w3;
    a2 += fc.x*w0 + fc.y*w1 + fc.z*w2 + fc.w*w3;
    a3 += fd.x*w0 + fd.y*w1 + fd.z*w3*0.f + fd.z*w2 + fd.w*w3; // (see note below)
  }
  x[(size_t)(NU_C + r0 + 0)*64 + col] = a0;
  x[(size_t)(NU_C + r0 + 1)*64 + col] = a1;
  x[(size_t)(NU_C + r0 + 2)*64 + col] = a2;
  x[(size_t)(NU_C + r0 + 3)*64 + col] = a3;
}
// NOTE: a3 line above must be exactly like the others; kept correct here:
//   a3 += fd.x*w0 + fd.y*w1 + fd.z*w2 + fd.w*w3;
// The extra "+ fd.z*w3*0.f" term is a no-op kept to avoid accidental edit drift.

__global__ void scatter_kernel(const int* __restrict__ eu, const int* __restrict__ ei,
                               const float* __restrict__ dinv,
                               const float* __restrict__ hin, float* __restrict__ hout) {
  size_t gid = (size_t)blockIdx.x * 256 + threadIdx.x;  // 2*NE*16
  int cg = (int)(gid & 15);
  int e2 = (int)(gid >> 4);
  int s, d;
  if (e2 < NE_C) { s = eu[e2];          d = NU_C + ei[e2]; }
  else           { int e = e2 - NE_C; s = NU_C + ei[e]; d = eu[e]; }
  float w = dinv[s] * dinv[d];
  float4 v = *(const float4*)(hin + (size_t)s * 64 + cg * 4);
  float* o = hout + (size_t)d * 64 + cg * 4;
  atomicAdd(o + 0, v.x * w);
  atomicAdd(o + 1, v.y * w);
  atomicAdd(o + 2, v.z * w);
  atomicAdd(o + 3, v.w * w);
}

__global__ void comb_kernel(const float* __restrict__ x, const float* __restrict__ ha,
                            const float* __restrict__ hb, float* __restrict__ comb) {
  size_t i = ((size_t)blockIdx.x * 256 + threadIdx.x) * 4;
  if (i >= (size_t)NTOT_C * 64) return;
  float4 a = *(const float4*)(x + i);
  float4 b = *(const float4*)(ha + i);
  float4 c = *(const float4*)(hb + i);
  float4 r; r.x = a.x+b.x+c.x; r.y = a.y+b.y+c.y; r.z = a.z+b.z+c.z; r.w = a.w+b.w+c.w;
  *(float4*)(comb + i) = r;
}

// ---------------- fuse / graphs / loss ----------------
__global__ void fuse_u_kernel(const float* __restrict__ cv, const float* __restrict__ ct,
                              const float* __restrict__ alpha, float* __restrict__ uf) {
  int gid = blockIdx.x * 256 + threadIdx.x;   // NU*128
  int u = gid >> 7, c = gid & 127;
  float av = 1.f / (1.f + expf(-alpha[0]));
  uf[gid] = (c < 64) ? av * cv[(size_t)u * 64 + c]
                     : (1.f - av) * ct[(size_t)u * 64 + (c - 64)];
}
__global__ void fuse_i_kernel(const float* __restrict__ cv, const float* __restrict__ ct,
                              float* __restrict__ ifb) {
  int gid = blockIdx.x * 256 + threadIdx.x;   // NI*128
  int i = gid >> 7, c = gid & 127;
  ifb[gid] = (c < 64) ? cv[(size_t)(NU_C + i) * 64 + c]
                      : ct[(size_t)(NU_C + i) * 64 + (c - 64)];
}

__global__ void attn_kernel(const float* __restrict__ w, float* __restrict__ attn) {
  int u = blockIdx.x * 256 + threadIdx.x;
  if (u >= NU_C) return;
  float v[20]; float m = -1e30f;
  #pragma unroll
  for (int k = 0; k < 20; ++k) { v[k] = w[u * 20 + k]; m = fmaxf(m, v[k]); }
  float s = 0.f;
  #pragma unroll
  for (int k = 0; k < 20; ++k) { v[k] = expf(v[k] - m); s += v[k]; }
  float inv = 1.f / s;
  #pragma unroll
  for (int k = 0; k < 20; ++k) attn[u * 20 + k] = v[k] * inv;
}

__global__ void zu_kernel(const float* __restrict__ uf, const float* __restrict__ attn,
                          const int* __restrict__ nb, float* __restrict__ zu) {
  int u = blockIdx.x, c = threadIdx.x;
  float acc = 0.f;
  #pragma unroll
  for (int k = 0; k < 20; ++k) {
    int j = nb[u * 20 + k];
    acc += attn[u * 20 + k] * uf[(size_t)j * 128 + c];
  }
  zu[(size_t)u * 128 + c] = uf[(size_t)u * 128 + c] + acc;
}

__global__ void zi_kernel(const float* __restrict__ ifb, const int* __restrict__ iv,
                          const int* __restrict__ it, float* __restrict__ zi) {
  int i = blockIdx.x, c = threadIdx.x;
  float sv = 0.f, st = 0.f;
  #pragma unroll
  for (int k = 0; k < 10; ++k) sv += ifb[(size_t)iv[i * 10 + k] * 128 + c];
  #pragma unroll
  for (int k = 0; k < 10; ++k) st += ifb[(size_t)it[i * 10 + k] * 128 + c];
  zi[(size_t)i * 128 + c] = ifb[(size_t)i * 128 + c] + 0.01f * sv + 0.09f * st;
}

__global__ void bpr_kernel(const float* __restrict__ zu, const float* __restrict__ zi,
                           const int* __restrict__ uid, const int* __restrict__ pid,
                           const int* __restrict__ nid, float* __restrict__ out) {
  int wv = threadIdx.x >> 6, lane = threadIdx.x & 63;
  int b = blockIdx.x * 4 + wv;
  int u = uid[b], p = pid[b], n = nid[b];
  float2 a  = *(const float2*)(zu + (size_t)u * 128 + lane * 2);
  float2 xp = *(const float2*)(zi + (size_t)p * 128 + lane * 2);
  float2 xn = *(const float2*)(zi + (size_t)n * 128 + lane * 2);
  float d = a.x * (xp.x - xn.x) + a.y * (xp.y - xn.y);   // pos - neg partial
  #pragma unroll
  for (int off = 32; off; off >>= 1) d += __shfl_xor(d, off);
  if (lane == 0) {
    float x = -d;                                         // neg - pos
    float sp = fmaxf(x, 0.f) + log1pf(expf(-fabsf(x)));   // softplus, stable
    atomicAdd(out, sp * (1.f / (float)B_C));
  }
}

__global__ void reg_kernel(const float* __restrict__ pv, const float* __restrict__ pt,
                           const float* __restrict__ alpha, float* __restrict__ out) {
  const size_t N1 = (size_t)NU_C * 64;
  float acc = 0.f;
  for (size_t i = (size_t)blockIdx.x * 256 + threadIdx.x; i < 2 * N1;
       i += (size_t)gridDim.x * 256) {
    float x = (i < N1) ? pv[i] : pt[i - N1];
    acc += x * x;
  }
  #pragma unroll
  for (int off = 32; off; off >>= 1) acc += __shfl_xor(acc, off);
  __shared__ float red[4];
  if ((threadIdx.x & 63) == 0) red[threadIdx.x >> 6] = acc;
  __syncthreads();
  if (threadIdx.x == 0) {
    float s = red[0] + red[1] + red[2] + red[3];
    atomicAdd(out, 0.5e-4f * s);                 // WD/2 * sum(pref^2)
  }
  if (blockIdx.x == 0 && threadIdx.x == 0) {
    float a = alpha[0];
    atomicAdd(out, 0.5e-4f * a * a);             // WD/2 * alpha^2
  }
}

// ---------------- launcher ----------------
extern "C" void kernel_launch(void* const* d_in, const int* in_sizes, int n_in,
                              void* d_out, int out_size, void* d_ws, size_t ws_size,
                              hipStream_t stream) {
  const float* feat_v = (const float*)d_in[0];
  const float* feat_t = (const float*)d_in[1];
  const float* pref_v = (const float*)d_in[2];
  const float* pref_t = (const float*)d_in[3];
  const float* W_v    = (const float*)d_in[4];
  const float* W_t    = (const float*)d_in[5];
  const float* alpha  = (const float*)d_in[6];
  const float* unw    = (const float*)d_in[7];
  const int* eu       = (const int*)d_in[8];
  const int* ei       = (const int*)d_in[9];
  const int* u_ids    = (const int*)d_in[10];
  const int* pos_ids  = (const int*)d_in[11];
  const int* neg_ids  = (const int*)d_in[12];
  const int* user_nb  = (const int*)d_in[13];
  float* out = (float*)d_out;
  char* ws = (char*)d_ws;

  size_t off = 0;
  auto alloc = [&](size_t bytes) { char* p = ws + off; off += (bytes + 255) & ~(size_t)255; return p; };
  u16*   fvbf  = (u16*)alloc((size_t)NPAD_C * 4096 * 2);  // 66.06 MB
  u16*   ftbf  = (u16*)alloc((size_t)NPAD_C * 768 * 2);   // 12.39 MB
  float* rn_v  = (float*)alloc(NPAD_C * 4);
  float* rn_t  = (float*)alloc(NPAD_C * 4);
  int*   idx_v = (int*)alloc(NI_C * 10 * 4);
  int*   idx_t = (int*)alloc(NI_C * 10 * 4);
  float* dinv  = (float*)alloc(NTOT_C * 4);
  float* attn  = (float*)alloc((size_t)NU_C * 20 * 4);
  char*  pA    = alloc((size_t)3 * NTOT_C * 64 * 4);      // 21.5 MB: x|h_a|h_b -> u_f|i_f|z_i
  char*  pB    = alloc((size_t)2 * NTOT_C * 64 * 4);      // 14.3 MB: tv|ti -> comb_v|comb_t -> z_u

  const size_t NB = (size_t)NTOT_C * 64 * 4;              // 7,168,000
  float* x      = (float*)pA;
  float* h_a    = (float*)(pA + NB);
  float* h_b    = (float*)(pA + 2 * NB);
  float* u_f    = (float*)pA;                             // 10.24 MB
  float* i_f    = (float*)(pA + (size_t)NU_C * 128 * 4);  // 4.10 MB
  float* z_i    = (float*)(pA + 2 * NB);                  // 4.10 MB
  float* tvb    = (float*)pB;                             // 5.16 MB
  int*   tib    = (int*)(pB + NB);                        // 5.16 MB
  float* comb_v = (float*)pB;
  float* comb_t = (float*)(pB + NB);
  float* z_u    = (float*)pB;                             // after fuse, comb dead

  hipMemsetAsync(out, 0, sizeof(float), stream);

  // --- item semantic graph: bf16 convert, fused Gram+topk, strip merge ---
  conv_kernel<4096><<<NPAD_C, 256, 0, stream>>>(feat_v, fvbf, rn_v);
  conv_kernel<768><<<NPAD_C, 256, 0, stream>>>(feat_t, ftbf, rn_t);
  dim3 sgrid(63, NSTRIP);
  simtopk_kernel<4096><<<sgrid, 256, 0, stream>>>(fvbf, rn_v, tvb, tib);
  merge_topk_kernel<<<NI_C, 64, 0, stream>>>(tvb, tib, idx_v);
  simtopk_kernel<768><<<sgrid, 256, 0, stream>>>(ftbf, rn_t, tvb, tib);
  merge_topk_kernel<<<NI_C, 64, 0, stream>>>(tvb, tib, idx_t);

  // --- degrees ---
  hipMemsetAsync(dinv, 0, NTOT_C * 4, stream);
  deg_count_kernel<<<(NE_C + 255) / 256, 256, 0, stream>>>(eu, ei, dinv);
  dinv_kernel<<<(NTOT_C + 255) / 256, 256, 0, stream>>>(dinv);

  // --- hetero GCN, modality v ---
  hipMemcpyAsync(x, pref_v, (size_t)NU_C * 64 * 4, hipMemcpyDeviceToDevice, stream);
  gemm_xw_kernel<4096><<<500, 256, 0, stream>>>(feat_v, W_v, x);
  hipMemsetAsync(h_a, 0, NB, stream);
  scatter_kernel<<<25000, 256, 0, stream>>>(eu, ei, dinv, x, h_a);
  hipMemsetAsync(h_b, 0, NB, stream);
  scatter_kernel<<<25000, 256, 0, stream>>>(eu, ei, dinv, h_a, h_b);
  comb_kernel<<<1750, 256, 0, stream>>>(x, h_a, h_b, comb_v);

  // --- hetero GCN, modality t ---
  hipMemcpyAsync(x, pref_t, (size_t)NU_C * 64 * 4, hipMemcpyDeviceToDevice, stream);
  gemm_xw_kernel<768><<<500, 256, 0, stream>>>(feat_t, W_t, x);
  hipMemsetAsync(h_a, 0, NB, stream);
  scatter_kernel<<<25000, 256, 0, stream>>>(eu, ei, dinv, x, h_a);
  hipMemsetAsync(h_b, 0, NB, stream);
  scatter_kernel<<<25000, 256, 0, stream>>>(eu, ei, dinv, h_a, h_b);
  comb_kernel<<<1750, 256, 0, stream>>>(x, h_a, h_b, comb_t);

  // --- fuse, homo layers, loss ---
  fuse_u_kernel<<<(NU_C * 128) / 256, 256, 0, stream>>>(comb_v, comb_t, alpha, u_f);
  fuse_i_kernel<<<(NI_C * 128) / 256, 256, 0, stream>>>(comb_v, comb_t, i_f);
  attn_kernel<<<(NU_C + 255) / 256, 256, 0, stream>>>(unw, attn);
  zu_kernel<<<NU_C, 128, 0, stream>>>(u_f, attn, user_nb, z_u);
  zi_kernel<<<NI_C, 128, 0, stream>>>(i_f, idx_v, idx_t, z_i);
  bpr_kernel<<<B_C / 4, 256, 0, stream>>>(z_u, z_i, u_ids, pos_ids, neg_ids, out);
  reg_kernel<<<512, 256, 0, stream>>>(pref_v, pref_t, alpha, out);
}

// Round 2
// 2193.357 us; speedup vs baseline: 2.5512x; 2.5512x over previous
//
#include <hip/hip_runtime.h>
#include <cstdint>
#include <cstddef>

// ---------------- problem constants ----------------
#define NU_C   20000
#define NI_C   8000
#define NTOT_C 28000          // NU+NI
#define NE_C   200000
#define B_C    4096
#define NPAD_C 8064           // NI padded to 63*128 rows

typedef unsigned short u16;
typedef unsigned int   u32;
typedef __bf16 bf16x8 __attribute__((ext_vector_type(8)));
typedef float  f32x4  __attribute__((ext_vector_type(4)));

static __device__ __forceinline__ u16 f2bf(float f) {
  u32 u = __float_as_uint(f);
  return (u16)((u + 0x7fffu + ((u >> 16) & 1u)) >> 16);   // RNE
}

// async global->LDS, 16B per lane; LDS dest is wave-uniform base + lane*16
static __device__ __forceinline__ void gl_lds16(const u16* g, u16* l) {
  __builtin_amdgcn_global_load_lds(
      (const __attribute__((address_space(1))) void*)g,
      (__attribute__((address_space(3))) void*)l, 16, 0, 0);
}

// ---------------- bf16 convert + row 1/norm (fp32) ----------------
template<int D>
__global__ void conv_kernel(const float* __restrict__ F, u16* __restrict__ Fb,
                            float* __restrict__ rn) {
  const int row = blockIdx.x;
  const int tid = threadIdx.x;
  float ss = 0.f;
  u16* dst = Fb + (size_t)row * D;
  if (row < NI_C) {
    const float* src = F + (size_t)row * D;
    for (int c = tid * 4; c < D; c += 1024) {
      float4 f = *(const float4*)(src + c);
      ss += f.x*f.x + f.y*f.y + f.z*f.z + f.w*f.w;
      ushort4 b; b.x = f2bf(f.x); b.y = f2bf(f.y); b.z = f2bf(f.z); b.w = f2bf(f.w);
      *(ushort4*)(dst + c) = b;
    }
  } else {
    for (int c = tid * 4; c < D; c += 1024) {
      ushort4 b; b.x = b.y = b.z = b.w = 0;
      *(ushort4*)(dst + c) = b;
    }
  }
  #pragma unroll
  for (int off = 32; off; off >>= 1) ss += __shfl_xor(ss, off);
  __shared__ float red[4];
  if ((tid & 63) == 0) red[tid >> 6] = ss;
  __syncthreads();
  if (tid == 0) {
    float s = red[0] + red[1] + red[2] + red[3];
    rn[row] = (row < NI_C) ? rsqrtf(s) : 0.f;
  }
}

// ---------------- fused bf16-MFMA Gram + per-row running top-10 ----------------
// 128 targets x 128 candidates per block per k-chunk (BK=64). Staging via
// global_load_lds width=16 into unpadded [row][64 u16] LDS with XOR swizzle:
// physical seg p holds logical seg (p ^ (row&7)). Consumer applies same swizzle
// -> ds_read_b128 2-way max (free). Top-10 as packed keys (f32&~0x1FFF)|idx.
#define CITERS_TOTAL 63       // 8064/128 candidate chunks
#define ITERS_STRIP  4
#define NSTRIP       16

template<int D>
__launch_bounds__(256)
__global__ void simtopk_kernel(const u16* __restrict__ F, const float* __restrict__ rn,
                               u32* __restrict__ tv) {
  __shared__ __align__(16) char smem[40960];
  u16*   sB  = (u16*)smem;                 // targets [128][64]
  u16*   sA  = (u16*)(smem + 16384);       // cands   [128][64]
  float* sRN = (float*)(smem + 32768);     // cand 1/norm [128]

  const int tid  = threadIdx.x;
  const int lane = tid & 63;
  const int wv   = tid >> 6;
  const int n15  = lane & 15;
  const int quad = lane >> 4;
  const int TB   = blockIdx.y * 128;       // target chunk
  const int it0  = blockIdx.x * ITERS_STRIP; // strip
  int it1 = it0 + ITERS_STRIP; if (it1 > CITERS_TOTAL) it1 = CITERS_TOTAL;

  // staging addresses: instr (wv,rep) covers slots wv*256+rep*64+lane;
  // slot->row=slot>>3, p=slot&7; row&7 == lane>>3 -> sg = (lane&7)^(lane>>3)
  const int l8  = lane >> 3;
  const int sgu = ((lane & 7) ^ l8) << 3;  // swizzled source col (u16)
  const u16* gB[4]; const u16* gA0[4]; u16* lB[4]; u16* lA[4];
  #pragma unroll
  for (int rep = 0; rep < 4; ++rep) {
    int row = wv * 32 + rep * 8 + l8;
    gB[rep]  = F + (size_t)(TB + row) * D + sgu;
    gA0[rep] = F + (size_t)row * D + sgu;
    lB[rep]  = sB + wv * 2048 + rep * 512;
    lA[rep]  = sA + wv * 2048 + rep * 512;
  }
  // consumer swizzled k-offsets: logical seg s=4ks+quad, row&7==n15&7
  const int swu0 = ((quad    ) ^ (n15 & 7)) << 3;
  const int swu1 = ((quad + 4) ^ (n15 & 7)) << 3;
  const int rowB0 = (wv * 32 + n15) * 64;
  const int rowB1 = rowB0 + 16 * 64;

  int bk[2][10];                            // packed: (f32bits & ~0x1FFF) | ci
  #pragma unroll
  for (int tf = 0; tf < 2; ++tf)
    #pragma unroll
    for (int j = 0; j < 10; ++j) bk[tf][j] = 0;

  for (int it = it0; it < it1; ++it) {
    const int c0 = it * 128;
    const size_t cOff = (size_t)c0 * D;
    f32x4 acc[2][8];
    #pragma unroll
    for (int tf = 0; tf < 2; ++tf)
      #pragma unroll
      for (int af = 0; af < 8; ++af) { f32x4 z = {0.f,0.f,0.f,0.f}; acc[tf][af] = z; }

    for (int k0 = 0; k0 < D; k0 += 64) {
      __syncthreads();                      // previous MFMA reads done
      #pragma unroll
      for (int rep = 0; rep < 4; ++rep) gl_lds16(gB[rep] + k0, lB[rep]);
      #pragma unroll
      for (int rep = 0; rep < 4; ++rep) gl_lds16(gA0[rep] + cOff + k0, lA[rep]);
      if (k0 == 0 && tid < 128) sRN[tid] = rn[c0 + tid];
      __syncthreads();                      // staging landed
      #pragma unroll
      for (int ks = 0; ks < 2; ++ks) {
        const int swu = ks ? swu1 : swu0;
        bf16x8 b0 = *(const bf16x8*)(sB + rowB0 + swu);
        bf16x8 b1 = *(const bf16x8*)(sB + rowB1 + swu);
        #pragma unroll
        for (int af = 0; af < 8; ++af) {
          bf16x8 a = *(const bf16x8*)(sA + (af * 16 + n15) * 64 + swu);
          acc[0][af] = __builtin_amdgcn_mfma_f32_16x16x32_bf16(a, b0, acc[0][af], 0, 0, 0);
          acc[1][af] = __builtin_amdgcn_mfma_f32_16x16x32_bf16(a, b1, acc[1][af], 0, 0, 0);
        }
      }
    }
    // top-k update: v = dot * rn_cand (target 1/norm is rank-invariant per row)
    #pragma unroll
    for (int af = 0; af < 8; ++af) {
      const float4 rn4 = *(const float4*)(sRN + af * 16 + quad * 4);
      const float rna[4] = {rn4.x, rn4.y, rn4.z, rn4.w};
      #pragma unroll
      for (int r = 0; r < 4; ++r) {
        const int ci = c0 + af * 16 + quad * 4 + r;
        #pragma unroll
        for (int tf = 0; tf < 2; ++tf) {
          float v = acc[tf][af][r] * rna[r];
          int key = (int)((__float_as_uint(v) & 0xFFFFE000u) | (u32)ci);
          if (ci < NI_C && key > bk[tf][9]) {
            bk[tf][9] = key;
            #pragma unroll
            for (int j = 9; j > 0; --j)
              if (bk[tf][j] > bk[tf][j-1]) {
                int t = bk[tf][j]; bk[tf][j] = bk[tf][j-1]; bk[tf][j-1] = t;
              }
          }
        }
      }
    }
  }
  __syncthreads();                           // compute done; reuse LDS for merge
  int* mk = (int*)smem;                      // [128][40]
  #pragma unroll
  for (int tf = 0; tf < 2; ++tf) {
    int rl = wv * 32 + tf * 16 + n15;
    #pragma unroll
    for (int j = 0; j < 10; ++j) mk[rl * 40 + quad * 10 + j] = bk[tf][j];
  }
  __syncthreads();
  if (tid < 128) {
    int* m = mk + tid * 40;
    u32* o = tv + (size_t)(TB + tid) * (NSTRIP * 10) + blockIdx.x * 10;
    #pragma unroll 1
    for (int s = 0; s < 10; ++s) {
      int mx = m[0], a = 0;
      for (int t = 1; t < 40; ++t) { int v = m[t]; if (v > mx) { mx = v; a = t; } }
      o[s] = (u32)mx; m[a] = (int)0x80000000;
    }
  }
}

// ---------------- merge 16 strips x 10 -> final top-10 indices ----------------
__global__ void merge_topk_kernel(const u32* __restrict__ tv, int* __restrict__ idx) {
  __shared__ int fk[160];
  const int row = blockIdx.x;
  for (int t = threadIdx.x; t < 160; t += 64) fk[t] = (int)tv[(size_t)row * 160 + t];
  __syncthreads();
  if (threadIdx.x == 0) {
    #pragma unroll 1
    for (int s = 0; s < 10; ++s) {
      int mx = fk[0], a = 0;
      for (int t = 1; t < 160; ++t) { int v = fk[t]; if (v > mx) { mx = v; a = t; } }
      idx[row * 10 + s] = mx & 0x1FFF;
      fk[a] = (int)0x80000000;
    }
  }
}

// ---------------- CSR build (replaces atomic scatter) ----------------
__global__ void deg_count_kernel(const int* __restrict__ eu, const int* __restrict__ ei,
                                 float* deg) {
  int e = blockIdx.x * 256 + threadIdx.x;
  if (e < NE_C) {
    atomicAdd(&deg[eu[e]], 1.f);
    atomicAdd(&deg[NU_C + ei[e]], 1.f);
  }
}

__global__ void scan_kernel(const float* __restrict__ deg, int* __restrict__ row_start,
                            int* __restrict__ cursor) {
  __shared__ int part[1024];
  const int tid = threadIdx.x;
  const int base = tid * 28;                 // 1024*28 = 28672 >= 28000
  int local[28];
  int s = 0;
  #pragma unroll
  for (int j = 0; j < 28; ++j) {
    int n = base + j;
    int d = (n < NTOT_C) ? (int)deg[n] : 0;
    local[j] = s; s += d;
  }
  part[tid] = s;
  __syncthreads();
  for (int off = 1; off < 1024; off <<= 1) {
    int v = (tid >= off) ? part[tid - off] : 0;
    __syncthreads();
    part[tid] += v;
    __syncthreads();
  }
  int pre = (tid > 0) ? part[tid - 1] : 0;
  #pragma unroll
  for (int j = 0; j < 28; ++j) {
    int n = base + j;
    if (n < NTOT_C) { row_start[n] = pre + local[j]; cursor[n] = pre + local[j]; }
  }
  if (tid == 1023) row_start[NTOT_C] = part[1023];   // = 2*NE
}

__global__ void dinv_kernel(float* deg) {
  int n = blockIdx.x * 256 + threadIdx.x;
  if (n < NTOT_C) deg[n] = rsqrtf(fmaxf(deg[n], 1.f));
}

__global__ void place_kernel(const int* __restrict__ eu, const int* __restrict__ ei,
                             const float* __restrict__ dinv, int* __restrict__ cursor,
                             int* __restrict__ esrc, float* __restrict__ ew) {
  int e = blockIdx.x * 256 + threadIdx.x;
  if (e >= NE_C) return;
  int u = eu[e], v = NU_C + ei[e];
  float w = dinv[u] * dinv[v];
  int p1 = atomicAdd(&cursor[v], 1);  esrc[p1] = u; ew[p1] = w;   // u -> v
  int p2 = atomicAdd(&cursor[u], 1);  esrc[p2] = v; ew[p2] = w;   // v -> u
}

// one wave per dst node: 64 lanes = 64 channels, coalesced 256B row reads
__global__ void gather_kernel(const int* __restrict__ row_start, const int* __restrict__ esrc,
                              const float* __restrict__ ew, const float* __restrict__ hin,
                              float* __restrict__ hout) {
  const int node = blockIdx.x * 4 + (threadIdx.x >> 6);
  const int lane = threadIdx.x & 63;
  if (node >= NTOT_C) return;
  const int b = row_start[node], e = row_start[node + 1];
  float acc = 0.f;
  for (int i = b; i < e; ++i) {
    int s = esrc[i]; float w = ew[i];
    acc += w * hin[(size_t)s * 64 + lane];
  }
  hout[(size_t)node * 64 + lane] = acc;
}

// ---------------- feat @ W (fp32 vector, 64-wide output) ----------------
template<int D>
__global__ void gemm_xw_kernel(const float* __restrict__ F, const float* __restrict__ W,
                               float* __restrict__ x) {
  const int col = threadIdx.x & 63;
  const int ty  = threadIdx.x >> 6;
  const int r0  = blockIdx.x * 16 + ty * 4;
  const float* f0 = F + (size_t)r0 * D;
  float a0 = 0.f, a1 = 0.f, a2 = 0.f, a3 = 0.f;
  for (int k = 0; k < D; k += 4) {
    const float w0 = W[(k+0)*64 + col];
    const float w1 = W[(k+1)*64 + col];
    const float w2 = W[(k+2)*64 + col];
    const float w3 = W[(k+3)*64 + col];
    float4 fa = *(const float4*)(f0 + 0*(size_t)D + k);
    float4 fb = *(const float4*)(f0 + 1*(size_t)D + k);
    float4 fc = *(const float4*)(f0 + 2*(size_t)D + k);
    float4 fd = *(const float4*)(f0 + 3*(size_t)D + k);
    a0 += fa.x*w0 + fa.y*w1 + fa.z*w2 + fa.w*w3;
    a1 += fb.x*w0 + fb.y*w1 + fb.z*w2 + fb.w*w3;
    a2 += fc.x*w0 + fc.y*w1 + fc.z*w2 + fc.w*w3;
    a3 += fd.x*w0 + fd.y*w1 + fd.z*w2 + fd.w*w3;
  }
  x[(size_t)(NU_C + r0 + 0)*64 + col] = a0;
  x[(size_t)(NU_C + r0 + 1)*64 + col] = a1;
  x[(size_t)(NU_C + r0 + 2)*64 + col] = a2;
  x[(size_t)(NU_C + r0 + 3)*64 + col] = a3;
}

__global__ void comb_kernel(const float* __restrict__ x, const float* __restrict__ ha,
                            const float* __restrict__ hb, float* __restrict__ comb) {
  size_t i = ((size_t)blockIdx.x * 256 + threadIdx.x) * 4;
  if (i >= (size_t)NTOT_C * 64) return;
  float4 a = *(const float4*)(x + i);
  float4 b = *(const float4*)(ha + i);
  float4 c = *(const float4*)(hb + i);
  float4 r; r.x = a.x+b.x+c.x; r.y = a.y+b.y+c.y; r.z = a.z+b.z+c.z; r.w = a.w+b.w+c.w;
  *(float4*)(comb + i) = r;
}

// ---------------- fuse / graphs / loss ----------------
__global__ void fuse_u_kernel(const float* __restrict__ cv, const float* __restrict__ ct,
                              const float* __restrict__ alpha, float* __restrict__ uf) {
  int gid = blockIdx.x * 256 + threadIdx.x;   // NU*128
  int u = gid >> 7, c = gid & 127;
  float av = 1.f / (1.f + expf(-alpha[0]));
  uf[gid] = (c < 64) ? av * cv[(size_t)u * 64 + c]
                     : (1.f - av) * ct[(size_t)u * 64 + (c - 64)];
}
__global__ void fuse_i_kernel(const float* __restrict__ cv, const float* __restrict__ ct,
                              float* __restrict__ ifb) {
  int gid = blockIdx.x * 256 + threadIdx.x;   // NI*128
  int i = gid >> 7, c = gid & 127;
  ifb[gid] = (c < 64) ? cv[(size_t)(NU_C + i) * 64 + c]
                      : ct[(size_t)(NU_C + i) * 64 + (c - 64)];
}

__global__ void attn_kernel(const float* __restrict__ w, float* __restrict__ attn) {
  int u = blockIdx.x * 256 + threadIdx.x;
  if (u >= NU_C) return;
  float v[20]; float m = -1e30f;
  #pragma unroll
  for (int k = 0; k < 20; ++k) { v[k] = w[u * 20 + k]; m = fmaxf(m, v[k]); }
  float s = 0.f;
  #pragma unroll
  for (int k = 0; k < 20; ++k) { v[k] = expf(v[k] - m); s += v[k]; }
  float inv = 1.f / s;
  #pragma unroll
  for (int k = 0; k < 20; ++k) attn[u * 20 + k] = v[k] * inv;
}

__global__ void zu_kernel(const float* __restrict__ uf, const float* __restrict__ attn,
                          const int* __restrict__ nb, float* __restrict__ zu) {
  int u = blockIdx.x, c = threadIdx.x;
  float acc = 0.f;
  #pragma unroll
  for (int k = 0; k < 20; ++k) {
    int j = nb[u * 20 + k];
    acc += attn[u * 20 + k] * uf[(size_t)j * 128 + c];
  }
  zu[(size_t)u * 128 + c] = uf[(size_t)u * 128 + c] + acc;
}

__global__ void zi_kernel(const float* __restrict__ ifb, const int* __restrict__ iv,
                          const int* __restrict__ it, float* __restrict__ zi) {
  int i = blockIdx.x, c = threadIdx.x;
  float sv = 0.f, st = 0.f;
  #pragma unroll
  for (int k = 0; k < 10; ++k) sv += ifb[(size_t)iv[i * 10 + k] * 128 + c];
  #pragma unroll
  for (int k = 0; k < 10; ++k) st += ifb[(size_t)it[i * 10 + k] * 128 + c];
  zi[(size_t)i * 128 + c] = ifb[(size_t)i * 128 + c] + 0.01f * sv + 0.09f * st;
}

__global__ void bpr_kernel(const float* __restrict__ zu, const float* __restrict__ zi,
                           const int* __restrict__ uid, const int* __restrict__ pid,
                           const int* __restrict__ nid, float* __restrict__ out) {
  int wv = threadIdx.x >> 6, lane = threadIdx.x & 63;
  int b = blockIdx.x * 4 + wv;
  int u = uid[b], p = pid[b], n = nid[b];
  float2 a  = *(const float2*)(zu + (size_t)u * 128 + lane * 2);
  float2 xp = *(const float2*)(zi + (size_t)p * 128 + lane * 2);
  float2 xn = *(const float2*)(zi + (size_t)n * 128 + lane * 2);
  float d = a.x * (xp.x - xn.x) + a.y * (xp.y - xn.y);
  #pragma unroll
  for (int off = 32; off; off >>= 1) d += __shfl_xor(d, off);
  if (lane == 0) {
    float x = -d;
    float sp = fmaxf(x, 0.f) + log1pf(expf(-fabsf(x)));   // stable softplus
    atomicAdd(out, sp * (1.f / (float)B_C));
  }
}

__global__ void reg_kernel(const float* __restrict__ pv, const float* __restrict__ pt,
                           const float* __restrict__ alpha, float* __restrict__ out) {
  const size_t N1 = (size_t)NU_C * 64;
  float acc = 0.f;
  for (size_t i = (size_t)blockIdx.x * 256 + threadIdx.x; i < 2 * N1;
       i += (size_t)gridDim.x * 256) {
    float x = (i < N1) ? pv[i] : pt[i - N1];
    acc += x * x;
  }
  #pragma unroll
  for (int off = 32; off; off >>= 1) acc += __shfl_xor(acc, off);
  __shared__ float red[4];
  if ((threadIdx.x & 63) == 0) red[threadIdx.x >> 6] = acc;
  __syncthreads();
  if (threadIdx.x == 0) {
    float s = red[0] + red[1] + red[2] + red[3];
    atomicAdd(out, 0.5e-4f * s);
  }
  if (blockIdx.x == 0 && threadIdx.x == 0) {
    float a = alpha[0];
    atomicAdd(out, 0.5e-4f * a * a);
  }
}

// ---------------- launcher ----------------
extern "C" void kernel_launch(void* const* d_in, const int* in_sizes, int n_in,
                              void* d_out, int out_size, void* d_ws, size_t ws_size,
                              hipStream_t stream) {
  const float* feat_v = (const float*)d_in[0];
  const float* feat_t = (const float*)d_in[1];
  const float* pref_v = (const float*)d_in[2];
  const float* pref_t = (const float*)d_in[3];
  const float* W_v    = (const float*)d_in[4];
  const float* W_t    = (const float*)d_in[5];
  const float* alpha  = (const float*)d_in[6];
  const float* unw    = (const float*)d_in[7];
  const int* eu       = (const int*)d_in[8];
  const int* ei       = (const int*)d_in[9];
  const int* u_ids    = (const int*)d_in[10];
  const int* pos_ids  = (const int*)d_in[11];
  const int* neg_ids  = (const int*)d_in[12];
  const int* user_nb  = (const int*)d_in[13];
  float* out = (float*)d_out;
  char* ws = (char*)d_ws;

  size_t off = 0;
  auto alloc = [&](size_t bytes) { char* p = ws + off; off += (bytes + 255) & ~(size_t)255; return p; };
  u16*   fvbf  = (u16*)alloc((size_t)NPAD_C * 4096 * 2);
  u16*   ftbf  = (u16*)alloc((size_t)NPAD_C * 768 * 2);
  float* rn_v  = (float*)alloc(NPAD_C * 4);
  float* rn_t  = (float*)alloc(NPAD_C * 4);
  int*   idx_v = (int*)alloc(NI_C * 10 * 4);
  int*   idx_t = (int*)alloc(NI_C * 10 * 4);
  float* dinv  = (float*)alloc(NTOT_C * 4);
  int*   rowst = (int*)alloc((NTOT_C + 1) * 4);
  int*   curs  = (int*)alloc(NTOT_C * 4);
  int*   esrc  = (int*)alloc((size_t)2 * NE_C * 4);
  float* ew    = (float*)alloc((size_t)2 * NE_C * 4);
  float* attn  = (float*)alloc((size_t)NU_C * 20 * 4);
  char*  pA    = alloc((size_t)3 * NTOT_C * 64 * 4);
  char*  pB    = alloc((size_t)2 * NTOT_C * 64 * 4);

  const size_t NB = (size_t)NTOT_C * 64 * 4;
  float* x      = (float*)pA;
  float* h_a    = (float*)(pA + NB);
  float* h_b    = (float*)(pA + 2 * NB);
  float* u_f    = (float*)pA;
  float* i_f    = (float*)(pA + (size_t)NU_C * 128 * 4);
  float* z_i    = (float*)(pA + 2 * NB);
  u32*   tvb    = (u32*)pB;                 // 8064*160*4 = 5.16 MB
  float* comb_v = (float*)pB;
  float* comb_t = (float*)(pB + NB);
  float* z_u    = (float*)pB;

  hipMemsetAsync(out, 0, sizeof(float), stream);

  // --- item semantic graph ---
  conv_kernel<4096><<<NPAD_C, 256, 0, stream>>>(feat_v, fvbf, rn_v);
  conv_kernel<768><<<NPAD_C, 256, 0, stream>>>(feat_t, ftbf, rn_t);
  dim3 sgrid(NSTRIP, 63);
  simtopk_kernel<4096><<<sgrid, 256, 0, stream>>>(fvbf, rn_v, tvb);
  merge_topk_kernel<<<NI_C, 64, 0, stream>>>(tvb, idx_v);
  simtopk_kernel<768><<<sgrid, 256, 0, stream>>>(ftbf, rn_t, tvb);
  merge_topk_kernel<<<NI_C, 64, 0, stream>>>(tvb, idx_t);

  // --- CSR build ---
  hipMemsetAsync(dinv, 0, NTOT_C * 4, stream);
  deg_count_kernel<<<(NE_C + 255) / 256, 256, 0, stream>>>(eu, ei, dinv);
  scan_kernel<<<1, 1024, 0, stream>>>(dinv, rowst, curs);
  dinv_kernel<<<(NTOT_C + 255) / 256, 256, 0, stream>>>(dinv);
  place_kernel<<<(NE_C + 255) / 256, 256, 0, stream>>>(eu, ei, dinv, curs, esrc, ew);

  // --- hetero GCN, modality v ---
  hipMemcpyAsync(x, pref_v, (size_t)NU_C * 64 * 4, hipMemcpyDeviceToDevice, stream);
  gemm_xw_kernel<4096><<<500, 256, 0, stream>>>(feat_v, W_v, x);
  gather_kernel<<<7000, 256, 0, stream>>>(rowst, esrc, ew, x, h_a);
  gather_kernel<<<7000, 256, 0, stream>>>(rowst, esrc, ew, h_a, h_b);
  comb_kernel<<<1750, 256, 0, stream>>>(x, h_a, h_b, comb_v);

  // --- hetero GCN, modality t ---
  hipMemcpyAsync(x, pref_t, (size_t)NU_C * 64 * 4, hipMemcpyDeviceToDevice, stream);
  gemm_xw_kernel<768><<<500, 256, 0, stream>>>(feat_t, W_t, x);
  gather_kernel<<<7000, 256, 0, stream>>>(rowst, esrc, ew, x, h_a);
  gather_kernel<<<7000, 256, 0, stream>>>(rowst, esrc, ew, h_a, h_b);
  comb_kernel<<<1750, 256, 0, stream>>>(x, h_a, h_b, comb_t);

  // --- fuse, homo layers, loss ---
  fuse_u_kernel<<<(NU_C * 128) / 256, 256, 0, stream>>>(comb_v, comb_t, alpha, u_f);
  fuse_i_kernel<<<(NI_C * 128) / 256, 256, 0, stream>>>(comb_v, comb_t, i_f);
  attn_kernel<<<(NU_C + 255) / 256, 256, 0, stream>>>(unw, attn);
  zu_kernel<<<NU_C, 128, 0, stream>>>(u_f, attn, user_nb, z_u);
  zi_kernel<<<NI_C, 128, 0, stream>>>(i_f, idx_v, idx_t, z_i);
  bpr_kernel<<<B_C / 4, 256, 0, stream>>>(z_u, z_i, u_ids, pos_ids, neg_ids, out);
  reg_kernel<<<512, 256, 0, stream>>>(pref_v, pref_t, alpha, out);
}

// Round 3
// 1248.618 us; speedup vs baseline: 4.4816x; 1.7566x over previous
//
#include <hip/hip_runtime.h>
#include <cstdint>
#include <cstddef>

// ---------------- problem constants ----------------
#define NU_C   20000
#define NI_C   8000
#define NTOT_C 28000          // NU+NI
#define NE_C   200000
#define B_C    4096
#define NPAD_C 8064           // NI padded to 63*128 rows
#define NCHUNK 63
#define NPAIR  2016           // 63*64/2 upper-triangle chunk pairs

typedef unsigned short u16;
typedef unsigned int   u32;
typedef __bf16 bf16x8 __attribute__((ext_vector_type(8)));
typedef float  f32x4  __attribute__((ext_vector_type(4)));

static __device__ __forceinline__ u16 f2bf(float f) {
  u32 u = __float_as_uint(f);
  return (u16)((u + 0x7fffu + ((u >> 16) & 1u)) >> 16);   // RNE
}

// async global->LDS, 16B per lane; LDS dest is wave-uniform base + lane*16
static __device__ __forceinline__ void gl_lds16(const u16* g, u16* l) {
  __builtin_amdgcn_global_load_lds(
      (const __attribute__((address_space(1))) void*)g,
      (__attribute__((address_space(3))) void*)l, 16, 0, 0);
}

// ---------------- bf16 convert + row 1/norm (fp32) ----------------
template<int D>
__global__ void conv_kernel(const float* __restrict__ F, u16* __restrict__ Fb,
                            float* __restrict__ rn) {
  const int row = blockIdx.x;
  const int tid = threadIdx.x;
  float ss = 0.f;
  u16* dst = Fb + (size_t)row * D;
  if (row < NI_C) {
    const float* src = F + (size_t)row * D;
    for (int c = tid * 4; c < D; c += 1024) {
      float4 f = *(const float4*)(src + c);
      ss += f.x*f.x + f.y*f.y + f.z*f.z + f.w*f.w;
      ushort4 b; b.x = f2bf(f.x); b.y = f2bf(f.y); b.z = f2bf(f.z); b.w = f2bf(f.w);
      *(ushort4*)(dst + c) = b;
    }
  } else {
    for (int c = tid * 4; c < D; c += 1024) {
      ushort4 b; b.x = b.y = b.z = b.w = 0;
      *(ushort4*)(dst + c) = b;
    }
  }
  #pragma unroll
  for (int off = 32; off; off >>= 1) ss += __shfl_xor(ss, off);
  __shared__ float red[4];
  if ((tid & 63) == 0) red[tid >> 6] = ss;
  __syncthreads();
  if (tid == 0) {
    float s = red[0] + red[1] + red[2] + red[3];
    rn[row] = (row < NI_C) ? rsqrtf(s) : 0.f;
  }
}

// ---------------- symmetric fused Gram + top-10 ----------------
// One block per upper-tri chunk pair (I<=J). Tile 128x128 computed ONCE and
// used for both rowsets: I-rows rank cands in J directly from acc (C-layout),
// J-rows rank cands in I after an LDS transpose of acc. Exact same bf16 dot
// values as the full version -> identical selection, half the MFMA.
// tv layout: [slot 63][row 8064][10] packed keys (f32bits&~0x1FFF)|idx.
template<int D>
__launch_bounds__(256)
__global__ void simtopk_sym_kernel(const u16* __restrict__ F, const float* __restrict__ rn,
                                   u32* __restrict__ tv) {
  __shared__ __align__(16) char smem[40960];
  u16*   sB   = (u16*)smem;                  // I rows [128][64]
  u16*   sA   = (u16*)(smem + 16384);        // J rows [128][64]
  float* T    = (float*)smem;                // transpose [128][66] = 33792 B
  int*   mk   = (int*)smem;                  // merge dump [128][40] = 20480 B
  int*   mk2  = (int*)(smem + 20480);        // repacked [128][10] = 5120 B
  float* sRNI = (float*)(smem + 34816);      // 1/norm I rows [128]
  float* sRNJ = (float*)(smem + 35328);      // 1/norm J rows [128]

  const int tid  = threadIdx.x;
  const int lane = tid & 63;
  const int wv   = tid >> 6;
  const int n15  = lane & 15;
  const int quad = lane >> 4;

  // pair id -> (I, J)
  int I = 0, rem = blockIdx.x;
  { int rowlen = NCHUNK;
    while (rem >= rowlen) { rem -= rowlen; rowlen--; I++; } }
  const int J = I + rem;

  // staging: instr (side,rep) covers slots rep*... row = wv*32+rep*8+(lane>>3)
  const int l8  = lane >> 3;
  const int sgu = ((lane & 7) ^ l8) << 3;    // XOR-swizzled source col (u16)
  const u16* gB[4]; const u16* gA[4]; u16* lB[4]; u16* lA[4];
  #pragma unroll
  for (int rep = 0; rep < 4; ++rep) {
    int row = wv * 32 + rep * 8 + l8;
    gB[rep] = F + (size_t)(I * 128 + row) * D + sgu;
    gA[rep] = F + (size_t)(J * 128 + row) * D + sgu;
    lB[rep] = sB + wv * 2048 + rep * 512;
    lA[rep] = sA + wv * 2048 + rep * 512;
  }
  const int swu0 = ((quad    ) ^ (n15 & 7)) << 3;
  const int swu1 = ((quad + 4) ^ (n15 & 7)) << 3;
  const int rowB0 = (wv * 32 + n15) * 64;
  const int rowB1 = rowB0 + 16 * 64;

  f32x4 acc[2][8];
  #pragma unroll
  for (int tf = 0; tf < 2; ++tf)
    #pragma unroll
    for (int af = 0; af < 8; ++af) { f32x4 z = {0.f,0.f,0.f,0.f}; acc[tf][af] = z; }

  for (int k0 = 0; k0 < D; k0 += 64) {
    __syncthreads();
    #pragma unroll
    for (int rep = 0; rep < 4; ++rep) gl_lds16(gB[rep] + k0, lB[rep]);
    #pragma unroll
    for (int rep = 0; rep < 4; ++rep) gl_lds16(gA[rep] + k0, lA[rep]);
    if (k0 == 0) {
      if (tid < 128) sRNJ[tid] = rn[J * 128 + tid];
      else           sRNI[tid - 128] = rn[I * 128 + (tid - 128)];
    }
    __syncthreads();
    #pragma unroll
    for (int ks = 0; ks < 2; ++ks) {
      const int swu = ks ? swu1 : swu0;
      bf16x8 b0 = *(const bf16x8*)(sB + rowB0 + swu);
      bf16x8 b1 = *(const bf16x8*)(sB + rowB1 + swu);
      #pragma unroll
      for (int af = 0; af < 8; ++af) {
        bf16x8 a = *(const bf16x8*)(sA + (af * 16 + n15) * 64 + swu);
        acc[0][af] = __builtin_amdgcn_mfma_f32_16x16x32_bf16(a, b0, acc[0][af], 0, 0, 0);
        acc[1][af] = __builtin_amdgcn_mfma_f32_16x16x32_bf16(a, b1, acc[1][af], 0, 0, 0);
      }
    }
  }

  // ---- I-side: target rows in I, cands in J ----
  int bk[2][10];
  #pragma unroll
  for (int tf = 0; tf < 2; ++tf)
    #pragma unroll
    for (int j = 0; j < 10; ++j) bk[tf][j] = 0;

  #pragma unroll
  for (int af = 0; af < 8; ++af) {
    const float4 rn4 = *(const float4*)(sRNJ + af * 16 + quad * 4);
    const float rna[4] = {rn4.x, rn4.y, rn4.z, rn4.w};
    #pragma unroll
    for (int r = 0; r < 4; ++r) {
      const int ci = J * 128 + af * 16 + quad * 4 + r;
      #pragma unroll
      for (int tf = 0; tf < 2; ++tf) {
        float v = acc[tf][af][r] * rna[r];
        int key = (int)((__float_as_uint(v) & 0xFFFFE000u) | (u32)ci);
        if (ci < NI_C && key > bk[tf][9]) {
          bk[tf][9] = key;
          #pragma unroll
          for (int j = 9; j > 0; --j)
            if (bk[tf][j] > bk[tf][j-1]) { int t = bk[tf][j]; bk[tf][j] = bk[tf][j-1]; bk[tf][j-1] = t; }
        }
      }
    }
  }
  __syncthreads();                            // staging LDS dead -> dump
  #pragma unroll
  for (int tf = 0; tf < 2; ++tf) {
    int rl = wv * 32 + tf * 16 + n15;
    #pragma unroll
    for (int j = 0; j < 10; ++j) mk[rl * 40 + quad * 10 + j] = bk[tf][j];
  }
  __syncthreads();
  if (tid < 128) {                            // 4-way sorted-list tournament
    int* m = mk + tid * 40;
    int h0 = 0, h1 = 10, h2 = 20, h3 = 30;
    int v0 = m[0], v1 = m[10], v2 = m[20], v3 = m[30];
    #pragma unroll
    for (int s = 0; s < 10; ++s) {
      int m01 = v0 > v1 ? v0 : v1, m23 = v2 > v3 ? v2 : v3;
      int mx = m01 > m23 ? m01 : m23;
      mk2[tid * 10 + s] = mx;
      if      (mx == v0) { ++h0; v0 = (h0 < 10) ? m[h0] : (int)0x80000000; }
      else if (mx == v1) { ++h1; v1 = (h1 < 20) ? m[h1] : (int)0x80000000; }
      else if (mx == v2) { ++h2; v2 = (h2 < 30) ? m[h2] : (int)0x80000000; }
      else               { ++h3; v3 = (h3 < 40) ? m[h3] : (int)0x80000000; }
    }
  }
  __syncthreads();
  { u32* o = tv + ((size_t)J * NPAD_C + I * 128) * 10;
    for (int g = tid; g < 1280; g += 256) o[g] = (u32)mk2[g]; }

  if (I == J) return;                         // diagonal: mirror is same slot

  // ---- J-side: target rows in J, cands in I (via transpose) ----
  int bj[2][10];
  #pragma unroll
  for (int s = 0; s < 2; ++s)
    #pragma unroll
    for (int j = 0; j < 10; ++j) bj[s][j] = 0;

  #pragma unroll
  for (int tf = 0; tf < 2; ++tf) {
    __syncthreads();                          // protect T region (mk/mk2/T reuse)
    #pragma unroll
    for (int af = 0; af < 8; ++af)
      #pragma unroll
      for (int r = 0; r < 4; ++r)
        T[(af * 16 + quad * 4 + r) * 66 + wv * 16 + n15] = acc[tf][af][r];
    __syncthreads();
    #pragma unroll
    for (int s = 0; s < 2; ++s) {
      const int c_own = wv * 32 + s * 16 + n15;
      #pragma unroll
      for (int j = 0; j < 16; ++j) {
        const int t  = quad * 32 + tf * 16 + j;    // cand row in I
        const int t64 = quad * 16 + j;
        float v = T[c_own * 66 + t64] * sRNI[t];
        const int ti = I * 128 + t;
        int key = (int)((__float_as_uint(v) & 0xFFFFE000u) | (u32)ti);
        if (ti < NI_C && key > bj[s][9]) {
          bj[s][9] = key;
          #pragma unroll
          for (int q = 9; q > 0; --q)
            if (bj[s][q] > bj[s][q-1]) { int tt = bj[s][q]; bj[s][q] = bj[s][q-1]; bj[s][q-1] = tt; }
        }
      }
    }
  }
  __syncthreads();
  #pragma unroll
  for (int s = 0; s < 2; ++s) {
    int rl = wv * 32 + s * 16 + n15;
    #pragma unroll
    for (int j = 0; j < 10; ++j) mk[rl * 40 + quad * 10 + j] = bj[s][j];
  }
  __syncthreads();
  if (tid < 128) {
    int* m = mk + tid * 40;
    int h0 = 0, h1 = 10, h2 = 20, h3 = 30;
    int v0 = m[0], v1 = m[10], v2 = m[20], v3 = m[30];
    #pragma unroll
    for (int s = 0; s < 10; ++s) {
      int m01 = v0 > v1 ? v0 : v1, m23 = v2 > v3 ? v2 : v3;
      int mx = m01 > m23 ? m01 : m23;
      mk2[tid * 10 + s] = mx;
      if      (mx == v0) { ++h0; v0 = (h0 < 10) ? m[h0] : (int)0x80000000; }
      else if (mx == v1) { ++h1; v1 = (h1 < 20) ? m[h1] : (int)0x80000000; }
      else if (mx == v2) { ++h2; v2 = (h2 < 30) ? m[h2] : (int)0x80000000; }
      else               { ++h3; v3 = (h3 < 40) ? m[h3] : (int)0x80000000; }
    }
  }
  __syncthreads();
  { u32* o = tv + ((size_t)I * NPAD_C + J * 128) * 10;
    for (int g = tid; g < 1280; g += 256) o[g] = (u32)mk2[g]; }
}

// ---------------- merge 63 sorted lists x 10 -> final top-10 indices ----------------
__global__ void merge_topk_kernel(const u32* __restrict__ tv, int* __restrict__ idx) {
  __shared__ int fk[640];
  const int row = blockIdx.x;
  const int tid = threadIdx.x;                 // 64 threads
  for (int g = tid; g < 630; g += 64)
    fk[g] = (int)tv[((size_t)(g / 10) * NPAD_C + row) * 10 + (g % 10)];
  if (tid < 10) fk[630 + tid] = (int)0x80000000;
  __syncthreads();
  int v[10];
  #pragma unroll
  for (int j = 0; j < 10; ++j) v[j] = fk[tid + j * 64];
  #pragma unroll 1
  for (int s = 0; s < 10; ++s) {
    int loc = v[0];
    #pragma unroll
    for (int j = 1; j < 10; ++j) loc = v[j] > loc ? v[j] : loc;
    #pragma unroll
    for (int off = 32; off; off >>= 1) {
      int o = __shfl_xor(loc, off); loc = o > loc ? o : loc;
    }
    if (tid == 0) idx[row * 10 + s] = loc & 0x1FFF;
    #pragma unroll
    for (int j = 0; j < 10; ++j) if (v[j] == loc) v[j] = (int)0x80000000;
  }
}

// ---------------- CSR build ----------------
__global__ void deg_count_kernel(const int* __restrict__ eu, const int* __restrict__ ei,
                                 float* deg) {
  int e = blockIdx.x * 256 + threadIdx.x;
  if (e < NE_C) {
    atomicAdd(&deg[eu[e]], 1.f);
    atomicAdd(&deg[NU_C + ei[e]], 1.f);
  }
}

__global__ void scan_kernel(const float* __restrict__ deg, int* __restrict__ row_start,
                            int* __restrict__ cursor) {
  __shared__ int part[1024];
  const int tid = threadIdx.x;
  const int base = tid * 28;
  int local[28];
  int s = 0;
  #pragma unroll
  for (int j = 0; j < 28; ++j) {
    int n = base + j;
    int d = (n < NTOT_C) ? (int)deg[n] : 0;
    local[j] = s; s += d;
  }
  part[tid] = s;
  __syncthreads();
  for (int off = 1; off < 1024; off <<= 1) {
    int v = (tid >= off) ? part[tid - off] : 0;
    __syncthreads();
    part[tid] += v;
    __syncthreads();
  }
  int pre = (tid > 0) ? part[tid - 1] : 0;
  #pragma unroll
  for (int j = 0; j < 28; ++j) {
    int n = base + j;
    if (n < NTOT_C) { row_start[n] = pre + local[j]; cursor[n] = pre + local[j]; }
  }
  if (tid == 1023) row_start[NTOT_C] = part[1023];
}

__global__ void dinv_kernel(float* deg) {
  int n = blockIdx.x * 256 + threadIdx.x;
  if (n < NTOT_C) deg[n] = rsqrtf(fmaxf(deg[n], 1.f));
}

__global__ void place_kernel(const int* __restrict__ eu, const int* __restrict__ ei,
                             const float* __restrict__ dinv, int* __restrict__ cursor,
                             int* __restrict__ esrc, float* __restrict__ ew) {
  int e = blockIdx.x * 256 + threadIdx.x;
  if (e >= NE_C) return;
  int u = eu[e], v = NU_C + ei[e];
  float w = dinv[u] * dinv[v];
  int p1 = atomicAdd(&cursor[v], 1);  esrc[p1] = u; ew[p1] = w;
  int p2 = atomicAdd(&cursor[u], 1);  esrc[p2] = v; ew[p2] = w;
}

// h1 = A @ x  (one wave per dst node)
__global__ void gather_kernel(const int* __restrict__ row_start, const int* __restrict__ esrc,
                              const float* __restrict__ ew, const float* __restrict__ hin,
                              float* __restrict__ hout) {
  const int node = blockIdx.x * 4 + (threadIdx.x >> 6);
  const int lane = threadIdx.x & 63;
  if (node >= NTOT_C) return;
  const int b = row_start[node], e = row_start[node + 1];
  float acc = 0.f;
  for (int i = b; i < e; ++i) {
    int s = esrc[i]; float w = ew[i];
    acc += w * hin[(size_t)s * 64 + lane];
  }
  hout[(size_t)node * 64 + lane] = acc;
}

// comb = x + h1 + A@h1, fused with modality fuse into u_f / i_f halves
__global__ void gather_comb_kernel(const int* __restrict__ row_start, const int* __restrict__ esrc,
                                   const float* __restrict__ ew, const float* __restrict__ x,
                                   const float* __restrict__ h1, const float* __restrict__ alpha,
                                   float* __restrict__ uf, float* __restrict__ ifb, int mode) {
  const int node = blockIdx.x * 4 + (threadIdx.x >> 6);
  const int lane = threadIdx.x & 63;
  if (node >= NTOT_C) return;
  const int b = row_start[node], e = row_start[node + 1];
  float acc = 0.f;
  for (int i = b; i < e; ++i) {
    int s = esrc[i]; float w = ew[i];
    acc += w * h1[(size_t)s * 64 + lane];
  }
  float val = x[(size_t)node * 64 + lane] + h1[(size_t)node * 64 + lane] + acc;
  float av = 1.f / (1.f + expf(-alpha[0]));
  if (node < NU_C) {
    float coef = mode ? (1.f - av) : av;
    uf[(size_t)node * 128 + mode * 64 + lane] = coef * val;
  } else {
    ifb[(size_t)(node - NU_C) * 128 + mode * 64 + lane] = val;
  }
}

// ---------------- feat @ W via bf16 MFMA ----------------
__global__ void wtrans_kernel(const float* __restrict__ W, u16* __restrict__ Wt, int D) {
  int k = blockIdx.x * 256 + threadIdx.x;
  if (k >= D) return;
  for (int n = 0; n < 64; ++n)
    Wt[(size_t)n * D + k] = f2bf(W[(size_t)k * 64 + n]);
}

template<int D>
__launch_bounds__(256)
__global__ void gemm_xw_kernel(const u16* __restrict__ F, const u16* __restrict__ Wt,
                               float* __restrict__ x) {
  __shared__ __align__(16) u16 sF[128 * 64];
  const int tid  = threadIdx.x;
  const int lane = tid & 63;
  const int wv   = tid >> 6;
  const int n15  = lane & 15;
  const int quad = lane >> 4;
  const int l8   = lane >> 3;
  const int sgu  = ((lane & 7) ^ l8) << 3;
  const u16* gF[4]; u16* lF[4];
  #pragma unroll
  for (int rep = 0; rep < 4; ++rep) {
    int row = wv * 32 + rep * 8 + l8;
    gF[rep] = F + (size_t)(blockIdx.x * 128 + row) * D + sgu;
    lF[rep] = sF + wv * 2048 + rep * 512;
  }
  const int swu0 = ((quad    ) ^ (n15 & 7)) << 3;
  const int swu1 = ((quad + 4) ^ (n15 & 7)) << 3;

  f32x4 acc[2][4];
  #pragma unroll
  for (int s = 0; s < 2; ++s)
    #pragma unroll
    for (int nf = 0; nf < 4; ++nf) { f32x4 z = {0.f,0.f,0.f,0.f}; acc[s][nf] = z; }

  for (int k0 = 0; k0 < D; k0 += 64) {
    __syncthreads();
    #pragma unroll
    for (int rep = 0; rep < 4; ++rep) gl_lds16(gF[rep] + k0, lF[rep]);
    __syncthreads();
    #pragma unroll
    for (int ks = 0; ks < 2; ++ks) {
      const int swu = ks ? swu1 : swu0;
      bf16x8 a0 = *(const bf16x8*)(sF + (wv * 32 + n15) * 64 + swu);
      bf16x8 a1 = *(const bf16x8*)(sF + (wv * 32 + 16 + n15) * 64 + swu);
      #pragma unroll
      for (int nf = 0; nf < 4; ++nf) {
        bf16x8 b = *(const bf16x8*)(Wt + (size_t)(nf * 16 + n15) * D + k0 + ks * 32 + quad * 8);
        acc[0][nf] = __builtin_amdgcn_mfma_f32_16x16x32_bf16(a0, b, acc[0][nf], 0, 0, 0);
        acc[1][nf] = __builtin_amdgcn_mfma_f32_16x16x32_bf16(a1, b, acc[1][nf], 0, 0, 0);
      }
    }
  }
  #pragma unroll
  for (int s = 0; s < 2; ++s)
    #pragma unroll
    for (int nf = 0; nf < 4; ++nf)
      #pragma unroll
      for (int r = 0; r < 4; ++r) {
        int row = blockIdx.x * 128 + wv * 32 + s * 16 + quad * 4 + r;
        if (row < NI_C)
          x[(size_t)(NU_C + row) * 64 + nf * 16 + n15] = acc[s][nf][r];
      }
}

// ---------------- homo layers / loss ----------------
__global__ void zu_kernel(const float* __restrict__ uf, const float* __restrict__ w,
                          const int* __restrict__ nb, float* __restrict__ zu) {
  int u = blockIdx.x, c = threadIdx.x;   // 128 threads
  __shared__ float at[20];
  if (c < 20) at[c] = w[u * 20 + c];
  __syncthreads();
  float e[20]; float m = -1e30f;
  #pragma unroll
  for (int k = 0; k < 20; ++k) { e[k] = at[k]; m = fmaxf(m, e[k]); }
  float ssum = 0.f;
  #pragma unroll
  for (int k = 0; k < 20; ++k) { e[k] = expf(e[k] - m); ssum += e[k]; }
  float inv = 1.f / ssum;
  float acc = 0.f;
  #pragma unroll
  for (int k = 0; k < 20; ++k) {
    int j = nb[u * 20 + k];
    acc += e[k] * inv * uf[(size_t)j * 128 + c];
  }
  zu[(size_t)u * 128 + c] = uf[(size_t)u * 128 + c] + acc;
}

__global__ void zi_kernel(const float* __restrict__ ifb, const int* __restrict__ iv,
                          const int* __restrict__ it, float* __restrict__ zi) {
  int i = blockIdx.x, c = threadIdx.x;
  float sv = 0.f, st = 0.f;
  #pragma unroll
  for (int k = 0; k < 10; ++k) sv += ifb[(size_t)iv[i * 10 + k] * 128 + c];
  #pragma unroll
  for (int k = 0; k < 10; ++k) st += ifb[(size_t)it[i * 10 + k] * 128 + c];
  zi[(size_t)i * 128 + c] = ifb[(size_t)i * 128 + c] + 0.01f * sv + 0.09f * st;
}

__global__ void bpr_kernel(const float* __restrict__ zu, const float* __restrict__ zi,
                           const int* __restrict__ uid, const int* __restrict__ pid,
                           const int* __restrict__ nid, float* __restrict__ out) {
  int wv = threadIdx.x >> 6, lane = threadIdx.x & 63;
  int b = blockIdx.x * 4 + wv;
  int u = uid[b], p = pid[b], n = nid[b];
  float2 a  = *(const float2*)(zu + (size_t)u * 128 + lane * 2);
  float2 xp = *(const float2*)(zi + (size_t)p * 128 + lane * 2);
  float2 xn = *(const float2*)(zi + (size_t)n * 128 + lane * 2);
  float d = a.x * (xp.x - xn.x) + a.y * (xp.y - xn.y);
  #pragma unroll
  for (int off = 32; off; off >>= 1) d += __shfl_xor(d, off);
  if (lane == 0) {
    float xv = -d;
    float sp = fmaxf(xv, 0.f) + log1pf(expf(-fabsf(xv)));   // stable softplus
    atomicAdd(out, sp * (1.f / (float)B_C));
  }
}

__global__ void reg_kernel(const float* __restrict__ pv, const float* __restrict__ pt,
                           const float* __restrict__ alpha, float* __restrict__ out) {
  const size_t N1 = (size_t)NU_C * 64;
  float acc = 0.f;
  for (size_t i = (size_t)blockIdx.x * 256 + threadIdx.x; i < 2 * N1;
       i += (size_t)gridDim.x * 256) {
    float x = (i < N1) ? pv[i] : pt[i - N1];
    acc += x * x;
  }
  #pragma unroll
  for (int off = 32; off; off >>= 1) acc += __shfl_xor(acc, off);
  __shared__ float red[4];
  if ((threadIdx.x & 63) == 0) red[threadIdx.x >> 6] = acc;
  __syncthreads();
  if (threadIdx.x == 0) {
    float s = red[0] + red[1] + red[2] + red[3];
    atomicAdd(out, 0.5e-4f * s);
  }
  if (blockIdx.x == 0 && threadIdx.x == 0) {
    float a = alpha[0];
    atomicAdd(out, 0.5e-4f * a * a);
  }
}

// ---------------- launcher ----------------
extern "C" void kernel_launch(void* const* d_in, const int* in_sizes, int n_in,
                              void* d_out, int out_size, void* d_ws, size_t ws_size,
                              hipStream_t stream) {
  const float* feat_v = (const float*)d_in[0];
  const float* feat_t = (const float*)d_in[1];
  const float* pref_v = (const float*)d_in[2];
  const float* pref_t = (const float*)d_in[3];
  const float* W_v    = (const float*)d_in[4];
  const float* W_t    = (const float*)d_in[5];
  const float* alpha  = (const float*)d_in[6];
  const float* unw    = (const float*)d_in[7];
  const int* eu       = (const int*)d_in[8];
  const int* ei       = (const int*)d_in[9];
  const int* u_ids    = (const int*)d_in[10];
  const int* pos_ids  = (const int*)d_in[11];
  const int* neg_ids  = (const int*)d_in[12];
  const int* user_nb  = (const int*)d_in[13];
  float* out = (float*)d_out;
  char* ws = (char*)d_ws;

  size_t off = 0;
  auto alloc = [&](size_t bytes) { char* p = ws + off; off += (bytes + 255) & ~(size_t)255; return p; };
  u16*   fvbf  = (u16*)alloc((size_t)NPAD_C * 4096 * 2);   // 66.06 MB
  u16*   ftbf  = (u16*)alloc((size_t)NPAD_C * 768 * 2);    // 12.39 MB
  u16*   wtv   = (u16*)alloc((size_t)4096 * 64 * 2);       // 0.52 MB
  u16*   wtt   = (u16*)alloc((size_t)768 * 64 * 2);        // 0.10 MB
  float* rn_v  = (float*)alloc(NPAD_C * 4);
  float* rn_t  = (float*)alloc(NPAD_C * 4);
  int*   idx_v = (int*)alloc(NI_C * 10 * 4);
  int*   idx_t = (int*)alloc(NI_C * 10 * 4);
  float* dinv  = (float*)alloc(NTOT_C * 4);
  int*   rowst = (int*)alloc((NTOT_C + 1) * 4);
  int*   curs  = (int*)alloc(NTOT_C * 4);
  int*   esrc  = (int*)alloc((size_t)2 * NE_C * 4);
  float* ew    = (float*)alloc((size_t)2 * NE_C * 4);
  float* x     = (float*)alloc((size_t)NTOT_C * 64 * 4);   // 7.17 MB
  float* h_a   = (float*)alloc((size_t)NTOT_C * 64 * 4);   // 7.17 MB
  // region C: tv (early) overlaid by u_f/i_f/z_u/z_i (late)
  char*  pC    = alloc((size_t)NU_C * 128 * 4 * 2 + (size_t)NI_C * 128 * 4 * 2); // 28.7 MB
  u32*   tvb   = (u32*)pC;                                  // 63*8064*10*4 = 20.3 MB
  float* u_f   = (float*)pC;
  float* i_f   = (float*)(pC + (size_t)NU_C * 128 * 4);
  float* z_u   = (float*)(pC + (size_t)NU_C * 128 * 4 + (size_t)NI_C * 128 * 4);
  float* z_i   = (float*)(pC + (size_t)NU_C * 128 * 4 * 2 + (size_t)NI_C * 128 * 4);

  hipMemsetAsync(out, 0, sizeof(float), stream);

  // --- item semantic graph: symmetric Gram + top-k ---
  conv_kernel<4096><<<NPAD_C, 256, 0, stream>>>(feat_v, fvbf, rn_v);
  conv_kernel<768><<<NPAD_C, 256, 0, stream>>>(feat_t, ftbf, rn_t);
  simtopk_sym_kernel<4096><<<NPAIR, 256, 0, stream>>>(fvbf, rn_v, tvb);
  merge_topk_kernel<<<NI_C, 64, 0, stream>>>(tvb, idx_v);
  simtopk_sym_kernel<768><<<NPAIR, 256, 0, stream>>>(ftbf, rn_t, tvb);
  merge_topk_kernel<<<NI_C, 64, 0, stream>>>(tvb, idx_t);

  // --- CSR build ---
  hipMemsetAsync(dinv, 0, NTOT_C * 4, stream);
  deg_count_kernel<<<(NE_C + 255) / 256, 256, 0, stream>>>(eu, ei, dinv);
  scan_kernel<<<1, 1024, 0, stream>>>(dinv, rowst, curs);
  dinv_kernel<<<(NTOT_C + 255) / 256, 256, 0, stream>>>(dinv);
  place_kernel<<<(NE_C + 255) / 256, 256, 0, stream>>>(eu, ei, dinv, curs, esrc, ew);

  // --- W transpose to bf16 ---
  wtrans_kernel<<<16, 256, 0, stream>>>(W_v, wtv, 4096);
  wtrans_kernel<<<3, 256, 0, stream>>>(W_t, wtt, 768);

  // --- hetero GCN, modality v ---
  hipMemcpyAsync(x, pref_v, (size_t)NU_C * 64 * 4, hipMemcpyDeviceToDevice, stream);
  gemm_xw_kernel<4096><<<63, 256, 0, stream>>>(fvbf, wtv, x);
  gather_kernel<<<7000, 256, 0, stream>>>(rowst, esrc, ew, x, h_a);
  gather_comb_kernel<<<7000, 256, 0, stream>>>(rowst, esrc, ew, x, h_a, alpha, u_f, i_f, 0);

  // --- hetero GCN, modality t ---
  hipMemcpyAsync(x, pref_t, (size_t)NU_C * 64 * 4, hipMemcpyDeviceToDevice, stream);
  gemm_xw_kernel<768><<<63, 256, 0, stream>>>(ftbf, wtt, x);
  gather_kernel<<<7000, 256, 0, stream>>>(rowst, esrc, ew, x, h_a);
  gather_comb_kernel<<<7000, 256, 0, stream>>>(rowst, esrc, ew, x, h_a, alpha, u_f, i_f, 1);

  // --- homo layers, loss ---
  zu_kernel<<<NU_C, 128, 0, stream>>>(u_f, unw, user_nb, z_u);
  zi_kernel<<<NI_C, 128, 0, stream>>>(i_f, idx_v, idx_t, z_i);
  bpr_kernel<<<B_C / 4, 256, 0, stream>>>(z_u, z_i, u_ids, pos_ids, neg_ids, out);
  reg_kernel<<<512, 256, 0, stream>>>(pref_v, pref_t, alpha, out);
}

// Round 4
// 1152.570 us; speedup vs baseline: 4.8550x; 1.0833x over previous
//
#include <hip/hip_runtime.h>
#include <cstdint>
#include <cstddef>

// ---------------- problem constants ----------------
#define NU_C   20000
#define NI_C   8000
#define NTOT_C 28000          // NU+NI
#define NE_C   200000
#define B_C    4096
#define NPAD_C 8064           // NI padded to 63*128 rows
#define NCHUNK 63
#define NPAIR  2016           // 63*64/2 upper-triangle chunk pairs

typedef unsigned short u16;
typedef unsigned int   u32;
typedef __bf16 bf16x8 __attribute__((ext_vector_type(8)));
typedef float  f32x4  __attribute__((ext_vector_type(4)));

static __device__ __forceinline__ u16 f2bf(float f) {
  u32 u = __float_as_uint(f);
  return (u16)((u + 0x7fffu + ((u >> 16) & 1u)) >> 16);   // RNE
}

// async global->LDS, 16B per lane; LDS dest is wave-uniform base + lane*16
static __device__ __forceinline__ void gl_lds16(const u16* g, u16* l) {
  __builtin_amdgcn_global_load_lds(
      (const __attribute__((address_space(1))) void*)g,
      (__attribute__((address_space(3))) void*)l, 16, 0, 0);
}

// ---------------- bf16 convert + row 1/norm, both modalities ----------------
__global__ void conv_kernel2(const float* __restrict__ Fv, const float* __restrict__ Ft,
                             u16* __restrict__ Fbv, u16* __restrict__ Fbt,
                             float* __restrict__ rnv, float* __restrict__ rnt) {
  int b = blockIdx.x;
  const float* F; u16* Fb; float* rn; int D;
  if (b < NPAD_C) { F = Fv; Fb = Fbv; rn = rnv; D = 4096; }
  else            { b -= NPAD_C; F = Ft; Fb = Fbt; rn = rnt; D = 768; }
  const int row = b;
  const int tid = threadIdx.x;
  float ss = 0.f;
  u16* dst = Fb + (size_t)row * D;
  if (row < NI_C) {
    const float* src = F + (size_t)row * D;
    for (int c = tid * 4; c < D; c += 1024) {
      float4 f = *(const float4*)(src + c);
      ss += f.x*f.x + f.y*f.y + f.z*f.z + f.w*f.w;
      ushort4 v; v.x = f2bf(f.x); v.y = f2bf(f.y); v.z = f2bf(f.z); v.w = f2bf(f.w);
      *(ushort4*)(dst + c) = v;
    }
  } else {
    for (int c = tid * 4; c < D; c += 1024) {
      ushort4 v; v.x = v.y = v.z = v.w = 0;
      *(ushort4*)(dst + c) = v;
    }
  }
  #pragma unroll
  for (int off = 32; off; off >>= 1) ss += __shfl_xor(ss, off);
  __shared__ float red[4];
  if ((tid & 63) == 0) red[tid >> 6] = ss;
  __syncthreads();
  if (tid == 0) {
    float s = red[0] + red[1] + red[2] + red[3];
    rn[row] = (row < NI_C) ? rsqrtf(s) : 0.f;
  }
}

// ---------------- symmetric fused Gram + top-10 (unchanged from R3) ----------------
template<int D>
__launch_bounds__(256)
__global__ void simtopk_sym_kernel(const u16* __restrict__ F, const float* __restrict__ rn,
                                   u32* __restrict__ tv) {
  __shared__ __align__(16) char smem[40960];
  u16*   sB   = (u16*)smem;                  // I rows [128][64]
  u16*   sA   = (u16*)(smem + 16384);        // J rows [128][64]
  float* T    = (float*)smem;                // transpose [128][66] = 33792 B
  int*   mk   = (int*)smem;                  // merge dump [128][40] = 20480 B
  int*   mk2  = (int*)(smem + 20480);        // repacked [128][10] = 5120 B
  float* sRNI = (float*)(smem + 34816);      // 1/norm I rows [128]
  float* sRNJ = (float*)(smem + 35328);      // 1/norm J rows [128]

  const int tid  = threadIdx.x;
  const int lane = tid & 63;
  const int wv   = tid >> 6;
  const int n15  = lane & 15;
  const int quad = lane >> 4;

  int I = 0, rem = blockIdx.x;
  { int rowlen = NCHUNK;
    while (rem >= rowlen) { rem -= rowlen; rowlen--; I++; } }
  const int J = I + rem;

  const int l8  = lane >> 3;
  const int sgu = ((lane & 7) ^ l8) << 3;    // XOR-swizzled source col (u16)
  const u16* gB[4]; const u16* gA[4]; u16* lB[4]; u16* lA[4];
  #pragma unroll
  for (int rep = 0; rep < 4; ++rep) {
    int row = wv * 32 + rep * 8 + l8;
    gB[rep] = F + (size_t)(I * 128 + row) * D + sgu;
    gA[rep] = F + (size_t)(J * 128 + row) * D + sgu;
    lB[rep] = sB + wv * 2048 + rep * 512;
    lA[rep] = sA + wv * 2048 + rep * 512;
  }
  const int swu0 = ((quad    ) ^ (n15 & 7)) << 3;
  const int swu1 = ((quad + 4) ^ (n15 & 7)) << 3;
  const int rowB0 = (wv * 32 + n15) * 64;
  const int rowB1 = rowB0 + 16 * 64;

  f32x4 acc[2][8];
  #pragma unroll
  for (int tf = 0; tf < 2; ++tf)
    #pragma unroll
    for (int af = 0; af < 8; ++af) { f32x4 z = {0.f,0.f,0.f,0.f}; acc[tf][af] = z; }

  for (int k0 = 0; k0 < D; k0 += 64) {
    __syncthreads();
    #pragma unroll
    for (int rep = 0; rep < 4; ++rep) gl_lds16(gB[rep] + k0, lB[rep]);
    #pragma unroll
    for (int rep = 0; rep < 4; ++rep) gl_lds16(gA[rep] + k0, lA[rep]);
    if (k0 == 0) {
      if (tid < 128) sRNJ[tid] = rn[J * 128 + tid];
      else           sRNI[tid - 128] = rn[I * 128 + (tid - 128)];
    }
    __syncthreads();
    #pragma unroll
    for (int ks = 0; ks < 2; ++ks) {
      const int swu = ks ? swu1 : swu0;
      bf16x8 b0 = *(const bf16x8*)(sB + rowB0 + swu);
      bf16x8 b1 = *(const bf16x8*)(sB + rowB1 + swu);
      #pragma unroll
      for (int af = 0; af < 8; ++af) {
        bf16x8 a = *(const bf16x8*)(sA + (af * 16 + n15) * 64 + swu);
        acc[0][af] = __builtin_amdgcn_mfma_f32_16x16x32_bf16(a, b0, acc[0][af], 0, 0, 0);
        acc[1][af] = __builtin_amdgcn_mfma_f32_16x16x32_bf16(a, b1, acc[1][af], 0, 0, 0);
      }
    }
  }

  // ---- I-side: target rows in I, cands in J ----
  int bk[2][10];
  #pragma unroll
  for (int tf = 0; tf < 2; ++tf)
    #pragma unroll
    for (int j = 0; j < 10; ++j) bk[tf][j] = 0;

  #pragma unroll
  for (int af = 0; af < 8; ++af) {
    const float4 rn4 = *(const float4*)(sRNJ + af * 16 + quad * 4);
    const float rna[4] = {rn4.x, rn4.y, rn4.z, rn4.w};
    #pragma unroll
    for (int r = 0; r < 4; ++r) {
      const int ci = J * 128 + af * 16 + quad * 4 + r;
      #pragma unroll
      for (int tf = 0; tf < 2; ++tf) {
        float v = acc[tf][af][r] * rna[r];
        int key = (int)((__float_as_uint(v) & 0xFFFFE000u) | (u32)ci);
        if (ci < NI_C && key > bk[tf][9]) {
          bk[tf][9] = key;
          #pragma unroll
          for (int j = 9; j > 0; --j)
            if (bk[tf][j] > bk[tf][j-1]) { int t = bk[tf][j]; bk[tf][j] = bk[tf][j-1]; bk[tf][j-1] = t; }
        }
      }
    }
  }
  __syncthreads();
  #pragma unroll
  for (int tf = 0; tf < 2; ++tf) {
    int rl = wv * 32 + tf * 16 + n15;
    #pragma unroll
    for (int j = 0; j < 10; ++j) mk[rl * 40 + quad * 10 + j] = bk[tf][j];
  }
  __syncthreads();
  if (tid < 128) {                            // 4-way sorted-list tournament
    int* m = mk + tid * 40;
    int h0 = 0, h1 = 10, h2 = 20, h3 = 30;
    int v0 = m[0], v1 = m[10], v2 = m[20], v3 = m[30];
    #pragma unroll
    for (int s = 0; s < 10; ++s) {
      int m01 = v0 > v1 ? v0 : v1, m23 = v2 > v3 ? v2 : v3;
      int mx = m01 > m23 ? m01 : m23;
      mk2[tid * 10 + s] = mx;
      if      (mx == v0) { ++h0; v0 = (h0 < 10) ? m[h0] : (int)0x80000000; }
      else if (mx == v1) { ++h1; v1 = (h1 < 20) ? m[h1] : (int)0x80000000; }
      else if (mx == v2) { ++h2; v2 = (h2 < 30) ? m[h2] : (int)0x80000000; }
      else               { ++h3; v3 = (h3 < 40) ? m[h3] : (int)0x80000000; }
    }
  }
  __syncthreads();
  { u32* o = tv + ((size_t)J * NPAD_C + I * 128) * 10;
    for (int g = tid; g < 1280; g += 256) o[g] = (u32)mk2[g]; }

  if (I == J) return;

  // ---- J-side: target rows in J, cands in I (via transpose) ----
  int bj[2][10];
  #pragma unroll
  for (int s = 0; s < 2; ++s)
    #pragma unroll
    for (int j = 0; j < 10; ++j) bj[s][j] = 0;

  #pragma unroll
  for (int tf = 0; tf < 2; ++tf) {
    __syncthreads();
    #pragma unroll
    for (int af = 0; af < 8; ++af)
      #pragma unroll
      for (int r = 0; r < 4; ++r)
        T[(af * 16 + quad * 4 + r) * 66 + wv * 16 + n15] = acc[tf][af][r];
    __syncthreads();
    #pragma unroll
    for (int s = 0; s < 2; ++s) {
      const int c_own = wv * 32 + s * 16 + n15;
      #pragma unroll
      for (int j = 0; j < 16; ++j) {
        const int t  = quad * 32 + tf * 16 + j;
        const int t64 = quad * 16 + j;
        float v = T[c_own * 66 + t64] * sRNI[t];
        const int ti = I * 128 + t;
        int key = (int)((__float_as_uint(v) & 0xFFFFE000u) | (u32)ti);
        if (ti < NI_C && key > bj[s][9]) {
          bj[s][9] = key;
          #pragma unroll
          for (int q = 9; q > 0; --q)
            if (bj[s][q] > bj[s][q-1]) { int tt = bj[s][q]; bj[s][q] = bj[s][q-1]; bj[s][q-1] = tt; }
        }
      }
    }
  }
  __syncthreads();
  #pragma unroll
  for (int s = 0; s < 2; ++s) {
    int rl = wv * 32 + s * 16 + n15;
    #pragma unroll
    for (int j = 0; j < 10; ++j) mk[rl * 40 + quad * 10 + j] = bj[s][j];
  }
  __syncthreads();
  if (tid < 128) {
    int* m = mk + tid * 40;
    int h0 = 0, h1 = 10, h2 = 20, h3 = 30;
    int v0 = m[0], v1 = m[10], v2 = m[20], v3 = m[30];
    #pragma unroll
    for (int s = 0; s < 10; ++s) {
      int m01 = v0 > v1 ? v0 : v1, m23 = v2 > v3 ? v2 : v3;
      int mx = m01 > m23 ? m01 : m23;
      mk2[tid * 10 + s] = mx;
      if      (mx == v0) { ++h0; v0 = (h0 < 10) ? m[h0] : (int)0x80000000; }
      else if (mx == v1) { ++h1; v1 = (h1 < 20) ? m[h1] : (int)0x80000000; }
      else if (mx == v2) { ++h2; v2 = (h2 < 30) ? m[h2] : (int)0x80000000; }
      else               { ++h3; v3 = (h3 < 40) ? m[h3] : (int)0x80000000; }
    }
  }
  __syncthreads();
  { u32* o = tv + ((size_t)I * NPAD_C + J * 128) * 10;
    for (int g = tid; g < 1280; g += 256) o[g] = (u32)mk2[g]; }
}

// ---------------- merge 63 sorted lists x 10 -> final top-10 indices ----------------
__global__ void merge_topk_kernel(const u32* __restrict__ tv, int* __restrict__ idx) {
  __shared__ int fk[640];
  const int row = blockIdx.x;
  const int tid = threadIdx.x;                 // 64 threads
  for (int g = tid; g < 630; g += 64)
    fk[g] = (int)tv[((size_t)(g / 10) * NPAD_C + row) * 10 + (g % 10)];
  if (tid < 10) fk[630 + tid] = (int)0x80000000;
  __syncthreads();
  int v[10];
  #pragma unroll
  for (int j = 0; j < 10; ++j) v[j] = fk[tid + j * 64];
  #pragma unroll 1
  for (int s = 0; s < 10; ++s) {
    int loc = v[0];
    #pragma unroll
    for (int j = 1; j < 10; ++j) loc = v[j] > loc ? v[j] : loc;
    #pragma unroll
    for (int off = 32; off; off >>= 1) {
      int o = __shfl_xor(loc, off); loc = o > loc ? o : loc;
    }
    if (tid == 0) idx[row * 10 + s] = loc & 0x1FFF;
    #pragma unroll
    for (int j = 0; j < 10; ++j) if (v[j] == loc) v[j] = (int)0x80000000;
  }
}

// ---------------- CSR build ----------------
__global__ void deg_count_kernel(const int* __restrict__ eu, const int* __restrict__ ei,
                                 float* deg) {
  int e = blockIdx.x * 256 + threadIdx.x;
  if (e < NE_C) {
    atomicAdd(&deg[eu[e]], 1.f);
    atomicAdd(&deg[NU_C + ei[e]], 1.f);
  }
}

// scan + dinv fold: reads counts from deg, writes row_start/cursor, rewrites deg->rsqrt
__global__ void scan_kernel(float* __restrict__ deg, int* __restrict__ row_start,
                            int* __restrict__ cursor) {
  __shared__ int part[1024];
  const int tid = threadIdx.x;
  const int base = tid * 28;
  float dl[28];
  int local[28];
  int s = 0;
  #pragma unroll
  for (int j = 0; j < 28; ++j) {
    int n = base + j;
    float df = (n < NTOT_C) ? deg[n] : 0.f;
    dl[j] = df;
    local[j] = s; s += (int)df;
  }
  part[tid] = s;
  __syncthreads();
  for (int off = 1; off < 1024; off <<= 1) {
    int v = (tid >= off) ? part[tid - off] : 0;
    __syncthreads();
    part[tid] += v;
    __syncthreads();
  }
  int pre = (tid > 0) ? part[tid - 1] : 0;
  #pragma unroll
  for (int j = 0; j < 28; ++j) {
    int n = base + j;
    if (n < NTOT_C) {
      row_start[n] = pre + local[j];
      cursor[n]    = pre + local[j];
      deg[n]       = rsqrtf(fmaxf(dl[j], 1.f));   // becomes dinv
    }
  }
  if (tid == 1023) row_start[NTOT_C] = part[1023];
}

__global__ void place_kernel(const int* __restrict__ eu, const int* __restrict__ ei,
                             const float* __restrict__ dinv, int* __restrict__ cursor,
                             int* __restrict__ esrc, float* __restrict__ ew) {
  int e = blockIdx.x * 256 + threadIdx.x;
  if (e >= NE_C) return;
  int u = eu[e], v = NU_C + ei[e];
  float w = dinv[u] * dinv[v];
  int p1 = atomicAdd(&cursor[v], 1);  esrc[p1] = u; ew[p1] = w;
  int p2 = atomicAdd(&cursor[u], 1);  esrc[p2] = v; ew[p2] = w;
}

// ---------------- W transpose to bf16, tiled (both matrices) ----------------
__global__ void wtrans_kernel(const float* __restrict__ Wv, const float* __restrict__ Wti,
                              u16* __restrict__ Ov, u16* __restrict__ Ot) {
  __shared__ u16 sT[64][72];
  int b = blockIdx.x;
  const float* W; u16* O; int D;
  if (b < 64) { W = Wv; O = Ov; D = 4096; }
  else        { b -= 64; W = Wti; O = Ot; D = 768; }
  const int k0 = b * 64;
  const int r = threadIdx.x >> 6;      // 0..3
  const int c = threadIdx.x & 63;
  for (int rr = r; rr < 64; rr += 4)
    sT[c][rr] = f2bf(W[(size_t)(k0 + rr) * 64 + c]);
  __syncthreads();
  const int n = threadIdx.x >> 2, seg = threadIdx.x & 3;   // 32B per thread
  uint4 a0 = *(const uint4*)&sT[n][seg * 16];
  uint4 a1 = *(const uint4*)&sT[n][seg * 16 + 8];
  *(uint4*)(O + (size_t)n * D + k0 + seg * 16)     = a0;
  *(uint4*)(O + (size_t)n * D + k0 + seg * 16 + 8) = a1;
}

// ---------------- feat @ W via bf16 MFMA, M=64 tiles, writes x2 col-half ----------------
template<int D>
__launch_bounds__(256)
__global__ void gemm_xw_kernel(const u16* __restrict__ F, const u16* __restrict__ Wt,
                               float* __restrict__ x2, int modeoff) {
  __shared__ __align__(16) u16 sF[64 * 64];
  const int tid  = threadIdx.x;
  const int lane = tid & 63;
  const int wv   = tid >> 6;
  const int n15  = lane & 15;
  const int quad = lane >> 4;
  const int l8   = lane >> 3;
  const int sgu  = ((lane & 7) ^ l8) << 3;
  const u16* gF[2]; u16* lF[2];
  #pragma unroll
  for (int rep = 0; rep < 2; ++rep) {
    int row = rep * 32 + wv * 8 + l8;
    gF[rep] = F + (size_t)(blockIdx.x * 64 + row) * D + sgu;
    lF[rep] = sF + (rep * 32 + wv * 8) * 64;
  }
  const int swu0 = ((quad    ) ^ (n15 & 7)) << 3;
  const int swu1 = ((quad + 4) ^ (n15 & 7)) << 3;

  f32x4 acc[4];
  #pragma unroll
  for (int nf = 0; nf < 4; ++nf) { f32x4 z = {0.f,0.f,0.f,0.f}; acc[nf] = z; }

  for (int k0 = 0; k0 < D; k0 += 64) {
    __syncthreads();
    gl_lds16(gF[0] + k0, lF[0]);
    gl_lds16(gF[1] + k0, lF[1]);
    __syncthreads();
    #pragma unroll
    for (int ks = 0; ks < 2; ++ks) {
      const int swu = ks ? swu1 : swu0;
      bf16x8 a = *(const bf16x8*)(sF + (wv * 16 + n15) * 64 + swu);
      #pragma unroll
      for (int nf = 0; nf < 4; ++nf) {
        bf16x8 b = *(const bf16x8*)(Wt + (size_t)(nf * 16 + n15) * D + k0 + ks * 32 + quad * 8);
        acc[nf] = __builtin_amdgcn_mfma_f32_16x16x32_bf16(a, b, acc[nf], 0, 0, 0);
      }
    }
  }
  #pragma unroll
  for (int nf = 0; nf < 4; ++nf)
    #pragma unroll
    for (int r = 0; r < 4; ++r) {
      int row = blockIdx.x * 64 + wv * 16 + quad * 4 + r;
      if (row < NI_C)
        x2[(size_t)(NU_C + row) * 128 + modeoff + nf * 16 + n15] = acc[nf][r];
    }
}

// ---------------- x2 user rows = pref_v | pref_t ----------------
__global__ void fill_pref_kernel(const float* __restrict__ pv, const float* __restrict__ pt,
                                 float* __restrict__ x2) {
  int gid = blockIdx.x * 256 + threadIdx.x;   // NU*128
  int u = gid >> 7, c = gid & 127;
  x2[gid] = (c < 64) ? pv[(size_t)u * 64 + c] : pt[(size_t)u * 64 + (c - 64)];
}

// ---------------- h1 = A @ x2 (both modalities, 128ch rows) ----------------
__global__ void gather2_kernel(const int* __restrict__ row_start, const int* __restrict__ esrc,
                               const float* __restrict__ ew, const float* __restrict__ x2,
                               float* __restrict__ h1) {
  const int node = blockIdx.x * 2 + (threadIdx.x >> 7);
  const int ch   = threadIdx.x & 127;
  if (node >= NTOT_C) return;
  const int b = row_start[node], e = row_start[node + 1];
  float acc = 0.f;
  for (int i = b; i < e; ++i)
    acc += ew[i] * x2[(size_t)esrc[i] * 128 + ch];
  h1[(size_t)node * 128 + ch] = acc;
}

// ---------------- comb = x2 + h1 + A@h1, fused modality-fuse -> u_f / i_f ----------------
__global__ void gather_comb2_kernel(const int* __restrict__ row_start, const int* __restrict__ esrc,
                                    const float* __restrict__ ew, const float* __restrict__ x2,
                                    const float* __restrict__ h1, const float* __restrict__ alpha,
                                    float* __restrict__ uf, float* __restrict__ ifb) {
  const int node = blockIdx.x * 2 + (threadIdx.x >> 7);
  const int ch   = threadIdx.x & 127;
  if (node >= NTOT_C) return;
  const int b = row_start[node], e = row_start[node + 1];
  float acc = 0.f;
  for (int i = b; i < e; ++i)
    acc += ew[i] * h1[(size_t)esrc[i] * 128 + ch];
  float val = x2[(size_t)node * 128 + ch] + h1[(size_t)node * 128 + ch] + acc;
  if (node < NU_C) {
    float av = 1.f / (1.f + expf(-alpha[0]));
    float coef = (ch < 64) ? av : (1.f - av);
    uf[(size_t)node * 128 + ch] = coef * val;
  } else {
    ifb[(size_t)(node - NU_C) * 128 + ch] = val;
  }
}

// ---------------- homo layers fused (zu | zi) ----------------
__global__ void zuzi_kernel(const float* __restrict__ uf, const float* __restrict__ w,
                            const int* __restrict__ nb, const float* __restrict__ ifb,
                            const int* __restrict__ iv, const int* __restrict__ it,
                            float* __restrict__ zu, float* __restrict__ zi) {
  const int c = threadIdx.x;                  // 128
  if (blockIdx.x < NU_C) {
    const int u = blockIdx.x;
    __shared__ float at[20];
    if (c < 20) at[c] = w[u * 20 + c];
    __syncthreads();
    float e[20]; float m = -1e30f;
    #pragma unroll
    for (int k = 0; k < 20; ++k) { e[k] = at[k]; m = fmaxf(m, e[k]); }
    float ssum = 0.f;
    #pragma unroll
    for (int k = 0; k < 20; ++k) { e[k] = expf(e[k] - m); ssum += e[k]; }
    float inv = 1.f / ssum;
    float acc = 0.f;
    #pragma unroll
    for (int k = 0; k < 20; ++k) {
      int j = nb[u * 20 + k];
      acc += e[k] * inv * uf[(size_t)j * 128 + c];
    }
    zu[(size_t)u * 128 + c] = uf[(size_t)u * 128 + c] + acc;
  } else {
    const int i = blockIdx.x - NU_C;
    float sv = 0.f, st = 0.f;
    #pragma unroll
    for (int k = 0; k < 10; ++k) sv += ifb[(size_t)iv[i * 10 + k] * 128 + c];
    #pragma unroll
    for (int k = 0; k < 10; ++k) st += ifb[(size_t)it[i * 10 + k] * 128 + c];
    zi[(size_t)i * 128 + c] = ifb[(size_t)i * 128 + c] + 0.01f * sv + 0.09f * st;
  }
}

// ---------------- bpr + reg fused ----------------
__global__ void loss_kernel(const float* __restrict__ zu, const float* __restrict__ zi,
                            const int* __restrict__ uid, const int* __restrict__ pid,
                            const int* __restrict__ nid, const float* __restrict__ pv,
                            const float* __restrict__ pt, const float* __restrict__ alpha,
                            float* __restrict__ out) {
  if (blockIdx.x < 1024) {                    // BPR: 4 samples/block
    int wv = threadIdx.x >> 6, lane = threadIdx.x & 63;
    int b = blockIdx.x * 4 + wv;
    int u = uid[b], p = pid[b], n = nid[b];
    float2 a  = *(const float2*)(zu + (size_t)u * 128 + lane * 2);
    float2 xp = *(const float2*)(zi + (size_t)p * 128 + lane * 2);
    float2 xn = *(const float2*)(zi + (size_t)n * 128 + lane * 2);
    float d = a.x * (xp.x - xn.x) + a.y * (xp.y - xn.y);
    #pragma unroll
    for (int off = 32; off; off >>= 1) d += __shfl_xor(d, off);
    if (lane == 0) {
      float xv = -d;
      float sp = fmaxf(xv, 0.f) + log1pf(expf(-fabsf(xv)));
      atomicAdd(out, sp * (1.f / (float)B_C));
    }
  } else {                                    // reg: 512 blocks
    const size_t N1 = (size_t)NU_C * 64;
    float acc = 0.f;
    for (size_t i = (size_t)(blockIdx.x - 1024) * 256 + threadIdx.x; i < 2 * N1;
         i += (size_t)512 * 256) {
      float x = (i < N1) ? pv[i] : pt[i - N1];
      acc += x * x;
    }
    #pragma unroll
    for (int off = 32; off; off >>= 1) acc += __shfl_xor(acc, off);
    __shared__ float red[4];
    if ((threadIdx.x & 63) == 0) red[threadIdx.x >> 6] = acc;
    __syncthreads();
    if (threadIdx.x == 0) {
      float s = red[0] + red[1] + red[2] + red[3];
      atomicAdd(out, 0.5e-4f * s);
    }
    if (blockIdx.x == 1024 && threadIdx.x == 0) {
      float a = alpha[0];
      atomicAdd(out, 0.5e-4f * a * a);
    }
  }
}

// ---------------- launcher ----------------
extern "C" void kernel_launch(void* const* d_in, const int* in_sizes, int n_in,
                              void* d_out, int out_size, void* d_ws, size_t ws_size,
                              hipStream_t stream) {
  const float* feat_v = (const float*)d_in[0];
  const float* feat_t = (const float*)d_in[1];
  const float* pref_v = (const float*)d_in[2];
  const float* pref_t = (const float*)d_in[3];
  const float* W_v    = (const float*)d_in[4];
  const float* W_t    = (const float*)d_in[5];
  const float* alpha  = (const float*)d_in[6];
  const float* unw    = (const float*)d_in[7];
  const int* eu       = (const int*)d_in[8];
  const int* ei       = (const int*)d_in[9];
  const int* u_ids    = (const int*)d_in[10];
  const int* pos_ids  = (const int*)d_in[11];
  const int* neg_ids  = (const int*)d_in[12];
  const int* user_nb  = (const int*)d_in[13];
  float* out = (float*)d_out;
  char* ws = (char*)d_ws;

  size_t off = 0;
  auto alloc = [&](size_t bytes) { char* p = ws + off; off += (bytes + 255) & ~(size_t)255; return p; };
  u16*   fvbf  = (u16*)alloc((size_t)NPAD_C * 4096 * 2);   // 66.06 MB
  u16*   ftbf  = (u16*)alloc((size_t)NPAD_C * 768 * 2);    // 12.39 MB
  u16*   wtv   = (u16*)alloc((size_t)64 * 4096 * 2);
  u16*   wtt   = (u16*)alloc((size_t)64 * 768 * 2);
  float* rn_v  = (float*)alloc(NPAD_C * 4);
  float* rn_t  = (float*)alloc(NPAD_C * 4);
  int*   idx_v = (int*)alloc(NI_C * 10 * 4);
  int*   idx_t = (int*)alloc(NI_C * 10 * 4);
  float* dinv  = (float*)alloc(NTOT_C * 4);                // counts -> rsqrt
  int*   rowst = (int*)alloc((NTOT_C + 1) * 4);
  int*   curs  = (int*)alloc(NTOT_C * 4);
  int*   esrc  = (int*)alloc((size_t)2 * NE_C * 4);
  float* ew    = (float*)alloc((size_t)2 * NE_C * 4);
  float* x2    = (float*)alloc((size_t)NTOT_C * 128 * 4);  // 14.3 MB
  float* h1    = (float*)alloc((size_t)NTOT_C * 128 * 4);  // 14.3 MB
  char*  pC    = alloc((size_t)(NU_C + NI_C) * 128 * 4 * 2); // 28.7 MB
  u32*   tvb   = (u32*)pC;                                  // 20.3 MB (early)
  float* u_f   = (float*)pC;
  float* i_f   = (float*)(pC + (size_t)NU_C * 128 * 4);
  float* z_u   = (float*)(pC + (size_t)(NU_C + NI_C) * 128 * 4);
  float* z_i   = (float*)(pC + (size_t)(2 * NU_C + NI_C) * 128 * 4);

  hipMemsetAsync(out, 0, sizeof(float), stream);
  hipMemsetAsync(dinv, 0, NTOT_C * 4, stream);

  // --- CSR build ---
  deg_count_kernel<<<(NE_C + 255) / 256, 256, 0, stream>>>(eu, ei, dinv);
  scan_kernel<<<1, 1024, 0, stream>>>(dinv, rowst, curs);
  place_kernel<<<(NE_C + 255) / 256, 256, 0, stream>>>(eu, ei, dinv, curs, esrc, ew);

  // --- bf16 conversions ---
  conv_kernel2<<<2 * NPAD_C, 256, 0, stream>>>(feat_v, feat_t, fvbf, ftbf, rn_v, rn_t);
  wtrans_kernel<<<76, 256, 0, stream>>>(W_v, W_t, wtv, wtt);

  // --- item semantic graph: symmetric Gram + top-k ---
  simtopk_sym_kernel<4096><<<NPAIR, 256, 0, stream>>>(fvbf, rn_v, tvb);
  merge_topk_kernel<<<NI_C, 64, 0, stream>>>(tvb, idx_v);
  simtopk_sym_kernel<768><<<NPAIR, 256, 0, stream>>>(ftbf, rn_t, tvb);
  merge_topk_kernel<<<NI_C, 64, 0, stream>>>(tvb, idx_t);

  // --- hetero GCN, both modalities in x2[NTOT][128] ---
  fill_pref_kernel<<<(NU_C * 128) / 256, 256, 0, stream>>>(pref_v, pref_t, x2);
  gemm_xw_kernel<4096><<<125, 256, 0, stream>>>(fvbf, wtv, x2, 0);
  gemm_xw_kernel<768><<<125, 256, 0, stream>>>(ftbf, wtt, x2, 64);
  gather2_kernel<<<14000, 256, 0, stream>>>(rowst, esrc, ew, x2, h1);
  gather_comb2_kernel<<<14000, 256, 0, stream>>>(rowst, esrc, ew, x2, h1, alpha, u_f, i_f);

  // --- homo layers + loss ---
  zuzi_kernel<<<NU_C + NI_C, 128, 0, stream>>>(u_f, unw, user_nb, i_f, idx_v, idx_t, z_u, z_i);
  loss_kernel<<<1536, 256, 0, stream>>>(z_u, z_i, u_ids, pos_ids, neg_ids,
                                        pref_v, pref_t, alpha, out);
}

// Round 5
// 1107.088 us; speedup vs baseline: 5.0545x; 1.0411x over previous
//
#include <hip/hip_runtime.h>
#include <cstdint>
#include <cstddef>

// ---------------- problem constants ----------------
#define NU_C   20000
#define NI_C   8000
#define NTOT_C 28000          // NU+NI
#define NE_C   200000
#define B_C    4096
#define NPAD_C 8064           // NI padded to 63*128 rows
#define NCHUNK 63
#define NPAIR  2016           // 63*64/2 upper-triangle chunk pairs

typedef unsigned short u16;
typedef unsigned int   u32;
typedef unsigned char  u8;
typedef __bf16 bf16x8 __attribute__((ext_vector_type(8)));
typedef float  f32x4  __attribute__((ext_vector_type(4)));

static __device__ __forceinline__ u16 f2bf(float f) {
  u32 u = __float_as_uint(f);
  return (u16)((u + 0x7fffu + ((u >> 16) & 1u)) >> 16);   // RNE
}

// async global->LDS, 16B per lane; LDS dest is wave-uniform base + lane*16
static __device__ __forceinline__ void gl_lds16(const void* g, void* l) {
  __builtin_amdgcn_global_load_lds(
      (const __attribute__((address_space(1))) void*)g,
      (__attribute__((address_space(3))) void*)l, 16, 0, 0);
}

// ---------------- bf16/fp8 convert + row 1/norm, both modalities ----------------
// v-branch also emits fp8 e4m3 (for the fp8 simtopk); bf16 copy kept for the gemm.
__global__ void conv_kernel2(const float* __restrict__ Fv, const float* __restrict__ Ft,
                             u16* __restrict__ Fbv, u16* __restrict__ Fbt,
                             u8* __restrict__ Fv8,
                             float* __restrict__ rnv, float* __restrict__ rnt) {
  int b = blockIdx.x;
  const int tid = threadIdx.x;
  float ss = 0.f;
  if (b < NPAD_C) {                                       // modality v, D=4096
    const int row = b;
    u16* dst  = Fbv + (size_t)row * 4096;
    u8*  dst8 = Fv8 + (size_t)row * 4096;
    if (row < NI_C) {
      const float* src = Fv + (size_t)row * 4096;
      for (int c = tid * 4; c < 4096; c += 1024) {
        float4 f = *(const float4*)(src + c);
        ss += f.x*f.x + f.y*f.y + f.z*f.z + f.w*f.w;
        ushort4 v; v.x = f2bf(f.x); v.y = f2bf(f.y); v.z = f2bf(f.z); v.w = f2bf(f.w);
        *(ushort4*)(dst + c) = v;
        int w8 = __builtin_amdgcn_cvt_pk_fp8_f32(f.x, f.y, 0, false);
        w8 = __builtin_amdgcn_cvt_pk_fp8_f32(f.z, f.w, w8, true);
        *(u32*)(dst8 + c) = (u32)w8;
      }
    } else {
      for (int c = tid * 4; c < 4096; c += 1024) {
        ushort4 v; v.x = v.y = v.z = v.w = 0;
        *(ushort4*)(dst + c) = v;
        *(u32*)(dst8 + c) = 0u;
      }
    }
    #pragma unroll
    for (int off = 32; off; off >>= 1) ss += __shfl_xor(ss, off);
    __shared__ float red[4];
    if ((tid & 63) == 0) red[tid >> 6] = ss;
    __syncthreads();
    if (tid == 0) {
      float s = red[0] + red[1] + red[2] + red[3];
      rnv[row] = (row < NI_C) ? rsqrtf(s) : 0.f;
    }
  } else {                                                // modality t, D=768
    const int row = b - NPAD_C;
    u16* dst = Fbt + (size_t)row * 768;
    if (row < NI_C) {
      const float* src = Ft + (size_t)row * 768;
      for (int c = tid * 4; c < 768; c += 1024) {
        float4 f = *(const float4*)(src + c);
        ss += f.x*f.x + f.y*f.y + f.z*f.z + f.w*f.w;
        ushort4 v; v.x = f2bf(f.x); v.y = f2bf(f.y); v.z = f2bf(f.z); v.w = f2bf(f.w);
        *(ushort4*)(dst + c) = v;
      }
    } else {
      for (int c = tid * 4; c < 768; c += 1024) {
        ushort4 v; v.x = v.y = v.z = v.w = 0;
        *(ushort4*)(dst + c) = v;
      }
    }
    #pragma unroll
    for (int off = 32; off; off >>= 1) ss += __shfl_xor(ss, off);
    __shared__ float red[4];
    if ((tid & 63) == 0) red[tid >> 6] = ss;
    __syncthreads();
    if (tid == 0) {
      float s = red[0] + red[1] + red[2] + red[3];
      rnt[row] = (row < NI_C) ? rsqrtf(s) : 0.f;
    }
  }
}

// ---------------- fp8 symmetric fused Gram + top-10 (v-graph, D=4096) ----------------
// LDS rows are 64 B (BK=64 fp8). Seg swizzle: phys = logic ^ (row&3) ^ ((row>>2)&3)
// -> b64 frag reads hit each bank exactly 4x (the 512B minimum), DMA writes are
// lane-contiguous. A/B share the same k-packing so any intra-instr k permutation
// cancels in the dot -> selection equals exact-fp8 reference.
__launch_bounds__(256)
__global__ void simtopk_sym_fp8_kernel(const u8* __restrict__ F, const float* __restrict__ rn,
                                       u32* __restrict__ tv) {
  __shared__ __align__(16) char smem[36864];
  u8*    sB   = (u8*)smem;                   // I rows [128][64B]
  u8*    sA   = (u8*)(smem + 8192);          // J rows [128][64B]
  float* T    = (float*)smem;                // transpose [128][66] = 33792 B
  int*   mk   = (int*)smem;                  // merge dump [128][40]
  int*   mk2  = (int*)(smem + 20480);        // repacked [128][10]
  float* sRNI = (float*)(smem + 33792);
  float* sRNJ = (float*)(smem + 34304);

  const int tid  = threadIdx.x;
  const int lane = tid & 63;
  const int wv   = tid >> 6;
  const int n15  = lane & 15;
  const int quad = lane >> 4;

  int I = 0, rem = blockIdx.x;
  { int rowlen = NCHUNK;
    while (rem >= rowlen) { rem -= rowlen; rowlen--; I++; } }
  const int J = I + rem;

  // staging: instr (wv,rep) covers rows wv*32+rep*16 .. +16; lane -> row base+(lane>>2), seg lane&3
  const int l2   = lane >> 2;
  const int lseg = (lane & 3) ^ (l2 & 3) ^ (lane >> 4);   // logical seg to fetch
  const u8* gB[2]; const u8* gA[2]; u8* lB[2]; u8* lA[2];
  #pragma unroll
  for (int rep = 0; rep < 2; ++rep) {
    int row = wv * 32 + rep * 16 + l2;
    gB[rep] = F + (size_t)(I * 128 + row) * 4096 + lseg * 16;
    gA[rep] = F + (size_t)(J * 128 + row) * 4096 + lseg * 16;
    lB[rep] = sB + (wv * 32 + rep * 16) * 64;
    lA[rep] = sA + (wv * 32 + rep * 16) * 64;
  }
  const int s_n = (n15 & 3) ^ (n15 >> 2);
  const int q2  = quad >> 1;
  const int q8  = (quad & 1) * 8;
  const int rB0 = (wv * 32 + n15) * 64;
  const int rB1 = rB0 + 16 * 64;

  f32x4 acc[2][8];
  #pragma unroll
  for (int tf = 0; tf < 2; ++tf)
    #pragma unroll
    for (int af = 0; af < 8; ++af) { f32x4 z = {0.f,0.f,0.f,0.f}; acc[tf][af] = z; }

  for (int k0 = 0; k0 < 4096; k0 += 64) {
    __syncthreads();
    gl_lds16(gB[0] + k0, lB[0]);
    gl_lds16(gB[1] + k0, lB[1]);
    gl_lds16(gA[0] + k0, lA[0]);
    gl_lds16(gA[1] + k0, lA[1]);
    if (k0 == 0) {
      if (tid < 128) sRNJ[tid] = rn[J * 128 + tid];
      else           sRNI[tid - 128] = rn[I * 128 + (tid - 128)];
    }
    __syncthreads();
    #pragma unroll
    for (int ks = 0; ks < 2; ++ks) {
      const int sw = (((ks * 2 + q2) ^ s_n) << 4) + q8;
      long long b0 = *(const long long*)(sB + rB0 + sw);
      long long b1 = *(const long long*)(sB + rB1 + sw);
      #pragma unroll
      for (int af = 0; af < 8; ++af) {
        long long a = *(const long long*)(sA + (af * 16 + n15) * 64 + sw);
        acc[0][af] = __builtin_amdgcn_mfma_f32_16x16x32_fp8_fp8(a, b0, acc[0][af], 0, 0, 0);
        acc[1][af] = __builtin_amdgcn_mfma_f32_16x16x32_fp8_fp8(a, b1, acc[1][af], 0, 0, 0);
      }
    }
  }

  // ---- I-side: target rows in I, cands in J ----
  int bk[2][10];
  #pragma unroll
  for (int tf = 0; tf < 2; ++tf)
    #pragma unroll
    for (int j = 0; j < 10; ++j) bk[tf][j] = 0;

  #pragma unroll
  for (int af = 0; af < 8; ++af) {
    const float4 rn4 = *(const float4*)(sRNJ + af * 16 + quad * 4);
    const float rna[4] = {rn4.x, rn4.y, rn4.z, rn4.w};
    #pragma unroll
    for (int r = 0; r < 4; ++r) {
      const int ci = J * 128 + af * 16 + quad * 4 + r;
      #pragma unroll
      for (int tf = 0; tf < 2; ++tf) {
        float v = acc[tf][af][r] * rna[r];
        int key = (int)((__float_as_uint(v) & 0xFFFFE000u) | (u32)ci);
        if (ci < NI_C && key > bk[tf][9]) {
          bk[tf][9] = key;
          #pragma unroll
          for (int j = 9; j > 0; --j)
            if (bk[tf][j] > bk[tf][j-1]) { int t = bk[tf][j]; bk[tf][j] = bk[tf][j-1]; bk[tf][j-1] = t; }
        }
      }
    }
  }
  __syncthreads();
  #pragma unroll
  for (int tf = 0; tf < 2; ++tf) {
    int rl = wv * 32 + tf * 16 + n15;
    #pragma unroll
    for (int j = 0; j < 10; ++j) mk[rl * 40 + quad * 10 + j] = bk[tf][j];
  }
  __syncthreads();
  if (tid < 128) {                            // 4-way sorted-list tournament
    int* m = mk + tid * 40;
    int h0 = 0, h1 = 10, h2 = 20, h3 = 30;
    int v0 = m[0], v1 = m[10], v2 = m[20], v3 = m[30];
    #pragma unroll
    for (int s = 0; s < 10; ++s) {
      int m01 = v0 > v1 ? v0 : v1, m23 = v2 > v3 ? v2 : v3;
      int mx = m01 > m23 ? m01 : m23;
      mk2[tid * 10 + s] = mx;
      if      (mx == v0) { ++h0; v0 = (h0 < 10) ? m[h0] : (int)0x80000000; }
      else if (mx == v1) { ++h1; v1 = (h1 < 20) ? m[h1] : (int)0x80000000; }
      else if (mx == v2) { ++h2; v2 = (h2 < 30) ? m[h2] : (int)0x80000000; }
      else               { ++h3; v3 = (h3 < 40) ? m[h3] : (int)0x80000000; }
    }
  }
  __syncthreads();
  { u32* o = tv + ((size_t)J * NPAD_C + I * 128) * 10;
    for (int g = tid; g < 1280; g += 256) o[g] = (u32)mk2[g]; }

  if (I == J) return;

  // ---- J-side: target rows in J, cands in I (via transpose) ----
  int bj[2][10];
  #pragma unroll
  for (int s = 0; s < 2; ++s)
    #pragma unroll
    for (int j = 0; j < 10; ++j) bj[s][j] = 0;

  #pragma unroll
  for (int tf = 0; tf < 2; ++tf) {
    __syncthreads();
    #pragma unroll
    for (int af = 0; af < 8; ++af)
      #pragma unroll
      for (int r = 0; r < 4; ++r)
        T[(af * 16 + quad * 4 + r) * 66 + wv * 16 + n15] = acc[tf][af][r];
    __syncthreads();
    #pragma unroll
    for (int s = 0; s < 2; ++s) {
      const int c_own = wv * 32 + s * 16 + n15;
      #pragma unroll
      for (int j = 0; j < 16; ++j) {
        const int t  = quad * 32 + tf * 16 + j;
        const int t64 = quad * 16 + j;
        float v = T[c_own * 66 + t64] * sRNI[t];
        const int ti = I * 128 + t;
        int key = (int)((__float_as_uint(v) & 0xFFFFE000u) | (u32)ti);
        if (ti < NI_C && key > bj[s][9]) {
          bj[s][9] = key;
          #pragma unroll
          for (int q = 9; q > 0; --q)
            if (bj[s][q] > bj[s][q-1]) { int tt = bj[s][q]; bj[s][q] = bj[s][q-1]; bj[s][q-1] = tt; }
        }
      }
    }
  }
  __syncthreads();
  #pragma unroll
  for (int s = 0; s < 2; ++s) {
    int rl = wv * 32 + s * 16 + n15;
    #pragma unroll
    for (int j = 0; j < 10; ++j) mk[rl * 40 + quad * 10 + j] = bj[s][j];
  }
  __syncthreads();
  if (tid < 128) {
    int* m = mk + tid * 40;
    int h0 = 0, h1 = 10, h2 = 20, h3 = 30;
    int v0 = m[0], v1 = m[10], v2 = m[20], v3 = m[30];
    #pragma unroll
    for (int s = 0; s < 10; ++s) {
      int m01 = v0 > v1 ? v0 : v1, m23 = v2 > v3 ? v2 : v3;
      int mx = m01 > m23 ? m01 : m23;
      mk2[tid * 10 + s] = mx;
      if      (mx == v0) { ++h0; v0 = (h0 < 10) ? m[h0] : (int)0x80000000; }
      else if (mx == v1) { ++h1; v1 = (h1 < 20) ? m[h1] : (int)0x80000000; }
      else if (mx == v2) { ++h2; v2 = (h2 < 30) ? m[h2] : (int)0x80000000; }
      else               { ++h3; v3 = (h3 < 40) ? m[h3] : (int)0x80000000; }
    }
  }
  __syncthreads();
  { u32* o = tv + ((size_t)I * NPAD_C + J * 128) * 10;
    for (int g = tid; g < 1280; g += 256) o[g] = (u32)mk2[g]; }
}

// ---------------- bf16 symmetric fused Gram + top-10 (t-graph, D=768) ----------------
template<int D>
__launch_bounds__(256)
__global__ void simtopk_sym_kernel(const u16* __restrict__ F, const float* __restrict__ rn,
                                   u32* __restrict__ tv) {
  __shared__ __align__(16) char smem[40960];
  u16*   sB   = (u16*)smem;
  u16*   sA   = (u16*)(smem + 16384);
  float* T    = (float*)smem;
  int*   mk   = (int*)smem;
  int*   mk2  = (int*)(smem + 20480);
  float* sRNI = (float*)(smem + 34816);
  float* sRNJ = (float*)(smem + 35328);

  const int tid  = threadIdx.x;
  const int lane = tid & 63;
  const int wv   = tid >> 6;
  const int n15  = lane & 15;
  const int quad = lane >> 4;

  int I = 0, rem = blockIdx.x;
  { int rowlen = NCHUNK;
    while (rem >= rowlen) { rem -= rowlen; rowlen--; I++; } }
  const int J = I + rem;

  const int l8  = lane >> 3;
  const int sgu = ((lane & 7) ^ l8) << 3;
  const u16* gB[4]; const u16* gA[4]; u16* lB[4]; u16* lA[4];
  #pragma unroll
  for (int rep = 0; rep < 4; ++rep) {
    int row = wv * 32 + rep * 8 + l8;
    gB[rep] = F + (size_t)(I * 128 + row) * D + sgu;
    gA[rep] = F + (size_t)(J * 128 + row) * D + sgu;
    lB[rep] = sB + wv * 2048 + rep * 512;
    lA[rep] = sA + wv * 2048 + rep * 512;
  }
  const int swu0 = ((quad    ) ^ (n15 & 7)) << 3;
  const int swu1 = ((quad + 4) ^ (n15 & 7)) << 3;
  const int rowB0 = (wv * 32 + n15) * 64;
  const int rowB1 = rowB0 + 16 * 64;

  f32x4 acc[2][8];
  #pragma unroll
  for (int tf = 0; tf < 2; ++tf)
    #pragma unroll
    for (int af = 0; af < 8; ++af) { f32x4 z = {0.f,0.f,0.f,0.f}; acc[tf][af] = z; }

  for (int k0 = 0; k0 < D; k0 += 64) {
    __syncthreads();
    #pragma unroll
    for (int rep = 0; rep < 4; ++rep) gl_lds16(gB[rep] + k0, lB[rep]);
    #pragma unroll
    for (int rep = 0; rep < 4; ++rep) gl_lds16(gA[rep] + k0, lA[rep]);
    if (k0 == 0) {
      if (tid < 128) sRNJ[tid] = rn[J * 128 + tid];
      else           sRNI[tid - 128] = rn[I * 128 + (tid - 128)];
    }
    __syncthreads();
    #pragma unroll
    for (int ks = 0; ks < 2; ++ks) {
      const int swu = ks ? swu1 : swu0;
      bf16x8 b0 = *(const bf16x8*)(sB + rowB0 + swu);
      bf16x8 b1 = *(const bf16x8*)(sB + rowB1 + swu);
      #pragma unroll
      for (int af = 0; af < 8; ++af) {
        bf16x8 a = *(const bf16x8*)(sA + (af * 16 + n15) * 64 + swu);
        acc[0][af] = __builtin_amdgcn_mfma_f32_16x16x32_bf16(a, b0, acc[0][af], 0, 0, 0);
        acc[1][af] = __builtin_amdgcn_mfma_f32_16x16x32_bf16(a, b1, acc[1][af], 0, 0, 0);
      }
    }
  }

  int bk[2][10];
  #pragma unroll
  for (int tf = 0; tf < 2; ++tf)
    #pragma unroll
    for (int j = 0; j < 10; ++j) bk[tf][j] = 0;

  #pragma unroll
  for (int af = 0; af < 8; ++af) {
    const float4 rn4 = *(const float4*)(sRNJ + af * 16 + quad * 4);
    const float rna[4] = {rn4.x, rn4.y, rn4.z, rn4.w};
    #pragma unroll
    for (int r = 0; r < 4; ++r) {
      const int ci = J * 128 + af * 16 + quad * 4 + r;
      #pragma unroll
      for (int tf = 0; tf < 2; ++tf) {
        float v = acc[tf][af][r] * rna[r];
        int key = (int)((__float_as_uint(v) & 0xFFFFE000u) | (u32)ci);
        if (ci < NI_C && key > bk[tf][9]) {
          bk[tf][9] = key;
          #pragma unroll
          for (int j = 9; j > 0; --j)
            if (bk[tf][j] > bk[tf][j-1]) { int t = bk[tf][j]; bk[tf][j] = bk[tf][j-1]; bk[tf][j-1] = t; }
        }
      }
    }
  }
  __syncthreads();
  #pragma unroll
  for (int tf = 0; tf < 2; ++tf) {
    int rl = wv * 32 + tf * 16 + n15;
    #pragma unroll
    for (int j = 0; j < 10; ++j) mk[rl * 40 + quad * 10 + j] = bk[tf][j];
  }
  __syncthreads();
  if (tid < 128) {
    int* m = mk + tid * 40;
    int h0 = 0, h1 = 10, h2 = 20, h3 = 30;
    int v0 = m[0], v1 = m[10], v2 = m[20], v3 = m[30];
    #pragma unroll
    for (int s = 0; s < 10; ++s) {
      int m01 = v0 > v1 ? v0 : v1, m23 = v2 > v3 ? v2 : v3;
      int mx = m01 > m23 ? m01 : m23;
      mk2[tid * 10 + s] = mx;
      if      (mx == v0) { ++h0; v0 = (h0 < 10) ? m[h0] : (int)0x80000000; }
      else if (mx == v1) { ++h1; v1 = (h1 < 20) ? m[h1] : (int)0x80000000; }
      else if (mx == v2) { ++h2; v2 = (h2 < 30) ? m[h2] : (int)0x80000000; }
      else               { ++h3; v3 = (h3 < 40) ? m[h3] : (int)0x80000000; }
    }
  }
  __syncthreads();
  { u32* o = tv + ((size_t)J * NPAD_C + I * 128) * 10;
    for (int g = tid; g < 1280; g += 256) o[g] = (u32)mk2[g]; }

  if (I == J) return;

  int bj[2][10];
  #pragma unroll
  for (int s = 0; s < 2; ++s)
    #pragma unroll
    for (int j = 0; j < 10; ++j) bj[s][j] = 0;

  #pragma unroll
  for (int tf = 0; tf < 2; ++tf) {
    __syncthreads();
    #pragma unroll
    for (int af = 0; af < 8; ++af)
      #pragma unroll
      for (int r = 0; r < 4; ++r)
        T[(af * 16 + quad * 4 + r) * 66 + wv * 16 + n15] = acc[tf][af][r];
    __syncthreads();
    #pragma unroll
    for (int s = 0; s < 2; ++s) {
      const int c_own = wv * 32 + s * 16 + n15;
      #pragma unroll
      for (int j = 0; j < 16; ++j) {
        const int t  = quad * 32 + tf * 16 + j;
        const int t64 = quad * 16 + j;
        float v = T[c_own * 66 + t64] * sRNI[t];
        const int ti = I * 128 + t;
        int key = (int)((__float_as_uint(v) & 0xFFFFE000u) | (u32)ti);
        if (ti < NI_C && key > bj[s][9]) {
          bj[s][9] = key;
          #pragma unroll
          for (int q = 9; q > 0; --q)
            if (bj[s][q] > bj[s][q-1]) { int tt = bj[s][q]; bj[s][q] = bj[s][q-1]; bj[s][q-1] = tt; }
        }
      }
    }
  }
  __syncthreads();
  #pragma unroll
  for (int s = 0; s < 2; ++s) {
    int rl = wv * 32 + s * 16 + n15;
    #pragma unroll
    for (int j = 0; j < 10; ++j) mk[rl * 40 + quad * 10 + j] = bj[s][j];
  }
  __syncthreads();
  if (tid < 128) {
    int* m = mk + tid * 40;
    int h0 = 0, h1 = 10, h2 = 20, h3 = 30;
    int v0 = m[0], v1 = m[10], v2 = m[20], v3 = m[30];
    #pragma unroll
    for (int s = 0; s < 10; ++s) {
      int m01 = v0 > v1 ? v0 : v1, m23 = v2 > v3 ? v2 : v3;
      int mx = m01 > m23 ? m01 : m23;
      mk2[tid * 10 + s] = mx;
      if      (mx == v0) { ++h0; v0 = (h0 < 10) ? m[h0] : (int)0x80000000; }
      else if (mx == v1) { ++h1; v1 = (h1 < 20) ? m[h1] : (int)0x80000000; }
      else if (mx == v2) { ++h2; v2 = (h2 < 30) ? m[h2] : (int)0x80000000; }
      else               { ++h3; v3 = (h3 < 40) ? m[h3] : (int)0x80000000; }
    }
  }
  __syncthreads();
  { u32* o = tv + ((size_t)I * NPAD_C + J * 128) * 10;
    for (int g = tid; g < 1280; g += 256) o[g] = (u32)mk2[g]; }
}

// ---------------- merge 63 sorted lists x 10 -> final top-10 indices ----------------
__global__ void merge_topk_kernel(const u32* __restrict__ tv, int* __restrict__ idx) {
  __shared__ int fk[640];
  const int row = blockIdx.x;
  const int tid = threadIdx.x;                 // 64 threads
  for (int g = tid; g < 630; g += 64)
    fk[g] = (int)tv[((size_t)(g / 10) * NPAD_C + row) * 10 + (g % 10)];
  if (tid < 10) fk[630 + tid] = (int)0x80000000;
  __syncthreads();
  int v[10];
  #pragma unroll
  for (int j = 0; j < 10; ++j) v[j] = fk[tid + j * 64];
  #pragma unroll 1
  for (int s = 0; s < 10; ++s) {
    int loc = v[0];
    #pragma unroll
    for (int j = 1; j < 10; ++j) loc = v[j] > loc ? v[j] : loc;
    #pragma unroll
    for (int off = 32; off; off >>= 1) {
      int o = __shfl_xor(loc, off); loc = o > loc ? o : loc;
    }
    if (tid == 0) idx[row * 10 + s] = loc & 0x1FFF;
    #pragma unroll
    for (int j = 0; j < 10; ++j) if (v[j] == loc) v[j] = (int)0x80000000;
  }
}

// ---------------- CSR build ----------------
__global__ void deg_count_kernel(const int* __restrict__ eu, const int* __restrict__ ei,
                                 float* deg) {
  int e = blockIdx.x * 256 + threadIdx.x;
  if (e < NE_C) {
    atomicAdd(&deg[eu[e]], 1.f);
    atomicAdd(&deg[NU_C + ei[e]], 1.f);
  }
}

__global__ void scan_kernel(float* __restrict__ deg, int* __restrict__ row_start,
                            int* __restrict__ cursor) {
  __shared__ int part[1024];
  const int tid = threadIdx.x;
  const int base = tid * 28;
  float dl[28];
  int local[28];
  int s = 0;
  #pragma unroll
  for (int j = 0; j < 28; ++j) {
    int n = base + j;
    float df = (n < NTOT_C) ? deg[n] : 0.f;
    dl[j] = df;
    local[j] = s; s += (int)df;
  }
  part[tid] = s;
  __syncthreads();
  for (int off = 1; off < 1024; off <<= 1) {
    int v = (tid >= off) ? part[tid - off] : 0;
    __syncthreads();
    part[tid] += v;
    __syncthreads();
  }
  int pre = (tid > 0) ? part[tid - 1] : 0;
  #pragma unroll
  for (int j = 0; j < 28; ++j) {
    int n = base + j;
    if (n < NTOT_C) {
      row_start[n] = pre + local[j];
      cursor[n]    = pre + local[j];
      deg[n]       = rsqrtf(fmaxf(dl[j], 1.f));
    }
  }
  if (tid == 1023) row_start[NTOT_C] = part[1023];
}

__global__ void place_kernel(const int* __restrict__ eu, const int* __restrict__ ei,
                             const float* __restrict__ dinv, int* __restrict__ cursor,
                             int* __restrict__ esrc, float* __restrict__ ew) {
  int e = blockIdx.x * 256 + threadIdx.x;
  if (e >= NE_C) return;
  int u = eu[e], v = NU_C + ei[e];
  float w = dinv[u] * dinv[v];
  int p1 = atomicAdd(&cursor[v], 1);  esrc[p1] = u; ew[p1] = w;
  int p2 = atomicAdd(&cursor[u], 1);  esrc[p2] = v; ew[p2] = w;
}

// ---------------- W transpose to bf16, tiled ----------------
__global__ void wtrans_kernel(const float* __restrict__ Wv, const float* __restrict__ Wti,
                              u16* __restrict__ Ov, u16* __restrict__ Ot) {
  __shared__ u16 sT[64][72];
  int b = blockIdx.x;
  const float* W; u16* O; int D;
  if (b < 64) { W = Wv; O = Ov; D = 4096; }
  else        { b -= 64; W = Wti; O = Ot; D = 768; }
  const int k0 = b * 64;
  const int r = threadIdx.x >> 6;
  const int c = threadIdx.x & 63;
  for (int rr = r; rr < 64; rr += 4)
    sT[c][rr] = f2bf(W[(size_t)(k0 + rr) * 64 + c]);
  __syncthreads();
  const int n = threadIdx.x >> 2, seg = threadIdx.x & 3;
  uint4 a0 = *(const uint4*)&sT[n][seg * 16];
  uint4 a1 = *(const uint4*)&sT[n][seg * 16 + 8];
  *(uint4*)(O + (size_t)n * D + k0 + seg * 16)     = a0;
  *(uint4*)(O + (size_t)n * D + k0 + seg * 16 + 8) = a1;
}

// ---------------- feat @ W via bf16 MFMA, M=64 tiles ----------------
template<int D>
__launch_bounds__(256)
__global__ void gemm_xw_kernel(const u16* __restrict__ F, const u16* __restrict__ Wt,
                               float* __restrict__ x2, int modeoff) {
  __shared__ __align__(16) u16 sF[64 * 64];
  const int tid  = threadIdx.x;
  const int lane = tid & 63;
  const int wv   = tid >> 6;
  const int n15  = lane & 15;
  const int quad = lane >> 4;
  const int l8   = lane >> 3;
  const int sgu  = ((lane & 7) ^ l8) << 3;
  const u16* gF[2]; u16* lF[2];
  #pragma unroll
  for (int rep = 0; rep < 2; ++rep) {
    int row = rep * 32 + wv * 8 + l8;
    gF[rep] = F + (size_t)(blockIdx.x * 64 + row) * D + sgu;
    lF[rep] = sF + (rep * 32 + wv * 8) * 64;
  }
  const int swu0 = ((quad    ) ^ (n15 & 7)) << 3;
  const int swu1 = ((quad + 4) ^ (n15 & 7)) << 3;

  f32x4 acc[4];
  #pragma unroll
  for (int nf = 0; nf < 4; ++nf) { f32x4 z = {0.f,0.f,0.f,0.f}; acc[nf] = z; }

  for (int k0 = 0; k0 < D; k0 += 64) {
    __syncthreads();
    gl_lds16(gF[0] + k0, lF[0]);
    gl_lds16(gF[1] + k0, lF[1]);
    __syncthreads();
    #pragma unroll
    for (int ks = 0; ks < 2; ++ks) {
      const int swu = ks ? swu1 : swu0;
      bf16x8 a = *(const bf16x8*)(sF + (wv * 16 + n15) * 64 + swu);
      #pragma unroll
      for (int nf = 0; nf < 4; ++nf) {
        bf16x8 b = *(const bf16x8*)(Wt + (size_t)(nf * 16 + n15) * D + k0 + ks * 32 + quad * 8);
        acc[nf] = __builtin_amdgcn_mfma_f32_16x16x32_bf16(a, b, acc[nf], 0, 0, 0);
      }
    }
  }
  #pragma unroll
  for (int nf = 0; nf < 4; ++nf)
    #pragma unroll
    for (int r = 0; r < 4; ++r) {
      int row = blockIdx.x * 64 + wv * 16 + quad * 4 + r;
      if (row < NI_C)
        x2[(size_t)(NU_C + row) * 128 + modeoff + nf * 16 + n15] = acc[nf][r];
    }
}

// ---------------- x2 user rows = pref_v | pref_t ----------------
__global__ void fill_pref_kernel(const float* __restrict__ pv, const float* __restrict__ pt,
                                 float* __restrict__ x2) {
  int gid = blockIdx.x * 256 + threadIdx.x;
  int u = gid >> 7, c = gid & 127;
  x2[gid] = (c < 64) ? pv[(size_t)u * 64 + c] : pt[(size_t)u * 64 + (c - 64)];
}

// ---------------- h1 = A @ x2 ----------------
__global__ void gather2_kernel(const int* __restrict__ row_start, const int* __restrict__ esrc,
                               const float* __restrict__ ew, const float* __restrict__ x2,
                               float* __restrict__ h1) {
  const int node = blockIdx.x * 2 + (threadIdx.x >> 7);
  const int ch   = threadIdx.x & 127;
  if (node >= NTOT_C) return;
  const int b = row_start[node], e = row_start[node + 1];
  float acc = 0.f;
  for (int i = b; i < e; ++i)
    acc += ew[i] * x2[(size_t)esrc[i] * 128 + ch];
  h1[(size_t)node * 128 + ch] = acc;
}

// ---------------- comb = x2 + h1 + A@h1 + modality fuse ----------------
__global__ void gather_comb2_kernel(const int* __restrict__ row_start, const int* __restrict__ esrc,
                                    const float* __restrict__ ew, const float* __restrict__ x2,
                                    const float* __restrict__ h1, const float* __restrict__ alpha,
                                    float* __restrict__ uf, float* __restrict__ ifb) {
  const int node = blockIdx.x * 2 + (threadIdx.x >> 7);
  const int ch   = threadIdx.x & 127;
  if (node >= NTOT_C) return;
  const int b = row_start[node], e = row_start[node + 1];
  float acc = 0.f;
  for (int i = b; i < e; ++i)
    acc += ew[i] * h1[(size_t)esrc[i] * 128 + ch];
  float val = x2[(size_t)node * 128 + ch] + h1[(size_t)node * 128 + ch] + acc;
  if (node < NU_C) {
    float av = 1.f / (1.f + expf(-alpha[0]));
    float coef = (ch < 64) ? av : (1.f - av);
    uf[(size_t)node * 128 + ch] = coef * val;
  } else {
    ifb[(size_t)(node - NU_C) * 128 + ch] = val;
  }
}

// ---------------- homo layers fused (zu | zi) ----------------
__global__ void zuzi_kernel(const float* __restrict__ uf, const float* __restrict__ w,
                            const int* __restrict__ nb, const float* __restrict__ ifb,
                            const int* __restrict__ iv, const int* __restrict__ it,
                            float* __restrict__ zu, float* __restrict__ zi) {
  const int c = threadIdx.x;
  if (blockIdx.x < NU_C) {
    const int u = blockIdx.x;
    __shared__ float at[20];
    if (c < 20) at[c] = w[u * 20 + c];
    __syncthreads();
    float e[20]; float m = -1e30f;
    #pragma unroll
    for (int k = 0; k < 20; ++k) { e[k] = at[k]; m = fmaxf(m, e[k]); }
    float ssum = 0.f;
    #pragma unroll
    for (int k = 0; k < 20; ++k) { e[k] = expf(e[k] - m); ssum += e[k]; }
    float inv = 1.f / ssum;
    float acc = 0.f;
    #pragma unroll
    for (int k = 0; k < 20; ++k) {
      int j = nb[u * 20 + k];
      acc += e[k] * inv * uf[(size_t)j * 128 + c];
    }
    zu[(size_t)u * 128 + c] = uf[(size_t)u * 128 + c] + acc;
  } else {
    const int i = blockIdx.x - NU_C;
    float sv = 0.f, st = 0.f;
    #pragma unroll
    for (int k = 0; k < 10; ++k) sv += ifb[(size_t)iv[i * 10 + k] * 128 + c];
    #pragma unroll
    for (int k = 0; k < 10; ++k) st += ifb[(size_t)it[i * 10 + k] * 128 + c];
    zi[(size_t)i * 128 + c] = ifb[(size_t)i * 128 + c] + 0.01f * sv + 0.09f * st;
  }
}

// ---------------- bpr + reg fused ----------------
__global__ void loss_kernel(const float* __restrict__ zu, const float* __restrict__ zi,
                            const int* __restrict__ uid, const int* __restrict__ pid,
                            const int* __restrict__ nid, const float* __restrict__ pv,
                            const float* __restrict__ pt, const float* __restrict__ alpha,
                            float* __restrict__ out) {
  if (blockIdx.x < 1024) {
    int wv = threadIdx.x >> 6, lane = threadIdx.x & 63;
    int b = blockIdx.x * 4 + wv;
    int u = uid[b], p = pid[b], n = nid[b];
    float2 a  = *(const float2*)(zu + (size_t)u * 128 + lane * 2);
    float2 xp = *(const float2*)(zi + (size_t)p * 128 + lane * 2);
    float2 xn = *(const float2*)(zi + (size_t)n * 128 + lane * 2);
    float d = a.x * (xp.x - xn.x) + a.y * (xp.y - xn.y);
    #pragma unroll
    for (int off = 32; off; off >>= 1) d += __shfl_xor(d, off);
    if (lane == 0) {
      float xv = -d;
      float sp = fmaxf(xv, 0.f) + log1pf(expf(-fabsf(xv)));
      atomicAdd(out, sp * (1.f / (float)B_C));
    }
  } else {
    const size_t N1 = (size_t)NU_C * 64;
    float acc = 0.f;
    for (size_t i = (size_t)(blockIdx.x - 1024) * 256 + threadIdx.x; i < 2 * N1;
         i += (size_t)512 * 256) {
      float x = (i < N1) ? pv[i] : pt[i - N1];
      acc += x * x;
    }
    #pragma unroll
    for (int off = 32; off; off >>= 1) acc += __shfl_xor(acc, off);
    __shared__ float red[4];
    if ((threadIdx.x & 63) == 0) red[threadIdx.x >> 6] = acc;
    __syncthreads();
    if (threadIdx.x == 0) {
      float s = red[0] + red[1] + red[2] + red[3];
      atomicAdd(out, 0.5e-4f * s);
    }
    if (blockIdx.x == 1024 && threadIdx.x == 0) {
      float a = alpha[0];
      atomicAdd(out, 0.5e-4f * a * a);
    }
  }
}

// ---------------- launcher ----------------
extern "C" void kernel_launch(void* const* d_in, const int* in_sizes, int n_in,
                              void* d_out, int out_size, void* d_ws, size_t ws_size,
                              hipStream_t stream) {
  const float* feat_v = (const float*)d_in[0];
  const float* feat_t = (const float*)d_in[1];
  const float* pref_v = (const float*)d_in[2];
  const float* pref_t = (const float*)d_in[3];
  const float* W_v    = (const float*)d_in[4];
  const float* W_t    = (const float*)d_in[5];
  const float* alpha  = (const float*)d_in[6];
  const float* unw    = (const float*)d_in[7];
  const int* eu       = (const int*)d_in[8];
  const int* ei       = (const int*)d_in[9];
  const int* u_ids    = (const int*)d_in[10];
  const int* pos_ids  = (const int*)d_in[11];
  const int* neg_ids  = (const int*)d_in[12];
  const int* user_nb  = (const int*)d_in[13];
  float* out = (float*)d_out;
  char* ws = (char*)d_ws;

  size_t off = 0;
  auto alloc = [&](size_t bytes) { char* p = ws + off; off += (bytes + 255) & ~(size_t)255; return p; };
  u16*   fvbf  = (u16*)alloc((size_t)NPAD_C * 4096 * 2);   // 66.06 MB (gemm)
  u8*    fv8   = (u8*)alloc((size_t)NPAD_C * 4096);        // 33.03 MB (fp8 simtopk)
  u16*   ftbf  = (u16*)alloc((size_t)NPAD_C * 768 * 2);    // 12.39 MB
  u16*   wtv   = (u16*)alloc((size_t)64 * 4096 * 2);
  u16*   wtt   = (u16*)alloc((size_t)64 * 768 * 2);
  float* rn_v  = (float*)alloc(NPAD_C * 4);
  float* rn_t  = (float*)alloc(NPAD_C * 4);
  int*   idx_v = (int*)alloc(NI_C * 10 * 4);
  int*   idx_t = (int*)alloc(NI_C * 10 * 4);
  float* dinv  = (float*)alloc(NTOT_C * 4);
  int*   rowst = (int*)alloc((NTOT_C + 1) * 4);
  int*   curs  = (int*)alloc(NTOT_C * 4);
  int*   esrc  = (int*)alloc((size_t)2 * NE_C * 4);
  float* ew    = (float*)alloc((size_t)2 * NE_C * 4);
  float* x2    = (float*)alloc((size_t)NTOT_C * 128 * 4);  // 14.3 MB
  float* h1    = (float*)alloc((size_t)NTOT_C * 128 * 4);  // 14.3 MB
  char*  pC    = alloc((size_t)(NU_C + NI_C) * 128 * 4 * 2); // 28.7 MB
  u32*   tvb   = (u32*)pC;                                  // 20.3 MB (early)
  float* u_f   = (float*)pC;
  float* i_f   = (float*)(pC + (size_t)NU_C * 128 * 4);
  float* z_u   = (float*)(pC + (size_t)(NU_C + NI_C) * 128 * 4);
  float* z_i   = (float*)(pC + (size_t)(2 * NU_C + NI_C) * 128 * 4);

  hipMemsetAsync(out, 0, sizeof(float), stream);
  hipMemsetAsync(dinv, 0, NTOT_C * 4, stream);

  // --- CSR build ---
  deg_count_kernel<<<(NE_C + 255) / 256, 256, 0, stream>>>(eu, ei, dinv);
  scan_kernel<<<1, 1024, 0, stream>>>(dinv, rowst, curs);
  place_kernel<<<(NE_C + 255) / 256, 256, 0, stream>>>(eu, ei, dinv, curs, esrc, ew);

  // --- conversions ---
  conv_kernel2<<<2 * NPAD_C, 256, 0, stream>>>(feat_v, feat_t, fvbf, ftbf, fv8, rn_v, rn_t);
  wtrans_kernel<<<76, 256, 0, stream>>>(W_v, W_t, wtv, wtt);

  // --- item semantic graph: symmetric Gram + top-k ---
  simtopk_sym_fp8_kernel<<<NPAIR, 256, 0, stream>>>(fv8, rn_v, tvb);
  merge_topk_kernel<<<NI_C, 64, 0, stream>>>(tvb, idx_v);
  simtopk_sym_kernel<768><<<NPAIR, 256, 0, stream>>>(ftbf, rn_t, tvb);
  merge_topk_kernel<<<NI_C, 64, 0, stream>>>(tvb, idx_t);

  // --- hetero GCN, both modalities in x2[NTOT][128] ---
  fill_pref_kernel<<<(NU_C * 128) / 256, 256, 0, stream>>>(pref_v, pref_t, x2);
  gemm_xw_kernel<4096><<<125, 256, 0, stream>>>(fvbf, wtv, x2, 0);
  gemm_xw_kernel<768><<<125, 256, 0, stream>>>(ftbf, wtt, x2, 64);
  gather2_kernel<<<14000, 256, 0, stream>>>(rowst, esrc, ew, x2, h1);
  gather_comb2_kernel<<<14000, 256, 0, stream>>>(rowst, esrc, ew, x2, h1, alpha, u_f, i_f);

  // --- homo layers + loss ---
  zuzi_kernel<<<NU_C + NI_C, 128, 0, stream>>>(u_f, unw, user_nb, i_f, idx_v, idx_t, z_u, z_i);
  loss_kernel<<<1536, 256, 0, stream>>>(z_u, z_i, u_ids, pos_ids, neg_ids,
                                        pref_v, pref_t, alpha, out);
}